// Round 2
// baseline (3774.842 us; speedup 1.0000x reference)
//
#include <hip/hip_runtime.h>
#include <hip/hip_bf16.h>

// Model: 4-layer Mamba2 TS model. B=32 L=1024 DM=256 DI=512 DST=64 NH=8 HD=64
// DC=4 Q=64 chunks=16 DIP=1160 CONVD=640 PRED=192 CO=21.
// I/O: ALL inputs float32, output float32 (threshold print proves no bf16 eps
// floor was applied -> harness kept reference dtypes). Internally: bf16 for
// MFMA GEMM operands, fp32 accumulation and SSD math.

typedef unsigned short ushort_t;
typedef unsigned int uint_t;
typedef __attribute__((ext_vector_type(8))) short short8;
typedef __attribute__((ext_vector_type(4))) float f32x4;

__device__ __forceinline__ float b2f(ushort_t u) {
    uint_t v = ((uint_t)u) << 16;
    return __builtin_bit_cast(float, v);
}
__device__ __forceinline__ ushort_t f2b(float f) {
    uint_t u = __builtin_bit_cast(uint_t, f);
    uint_t r = (u + 0x7FFFu + ((u >> 16) & 1u)) >> 16;
    return (ushort_t)r;
}
__device__ __forceinline__ float silu_f(float x) {
    return x / (1.f + __expf(-x));
}

// ---------------- f32 -> bf16 weight convert ----------------
__global__ __launch_bounds__(256) void cvt_kernel(const float* __restrict__ in,
        ushort_t* __restrict__ out, int n) {
    int i = blockIdx.x * 256 + threadIdx.x;
    if (i < n) out[i] = f2b(in[i]);
}

// ---------------- stats: per (b,c) mean/std over L ----------------
__global__ __launch_bounds__(256) void stats_kernel(const float* __restrict__ xe,
        float* __restrict__ meanb, float* __restrict__ stdb, float* __restrict__ rstdb) {
    int bi = blockIdx.x;            // 0..671
    int b = bi / 21, c = bi - b * 21;
    int tid = threadIdx.x;
    float s = 0.f, s2 = 0.f;
    for (int l = tid; l < 1024; l += 256) {
        float v = xe[(b * 1024 + l) * 21 + c];
        s += v; s2 += v * v;
    }
    __shared__ float r1[4], r2[4];
    for (int o = 32; o > 0; o >>= 1) { s += __shfl_down(s, o, 64); s2 += __shfl_down(s2, o, 64); }
    if ((tid & 63) == 0) { r1[tid >> 6] = s; r2[tid >> 6] = s2; }
    __syncthreads();
    if (tid == 0) {
        float S = r1[0] + r1[1] + r1[2] + r1[3];
        float S2 = r2[0] + r2[1] + r2[2] + r2[3];
        float m = S * (1.f / 1024.f);
        float var = S2 * (1.f / 1024.f) - m * m;
        float sd = sqrtf(var + 1e-5f);
        meanb[bi] = m; stdb[bi] = sd; rstdb[bi] = 1.f / sd;
    }
}

// ---------------- embedding: token conv(3, wrap) + pos-emb + time-emb ----------------
__global__ __launch_bounds__(256) void embed_kernel(const float* __restrict__ xe,
        const float* __restrict__ xm, const float* __restrict__ tokw,
        const float* __restrict__ tembw, const float* __restrict__ meanb,
        const float* __restrict__ rstdb, float* __restrict__ h, ushort_t* __restrict__ hbf) {
    int blk = blockIdx.x;               // b*1024 + l
    int b = blk >> 10, l = blk & 1023;
    int tid = threadIdx.x;
    __shared__ float xr[3][21];
    __shared__ float xmr[4];
    if (tid < 63) {
        int k = tid / 21, c = tid - k * 21;
        int ll = (l + k - 1 + 1024) & 1023;
        xr[k][c] = (xe[(b * 1024 + ll) * 21 + c] - meanb[b * 21 + c]) * rstdb[b * 21 + c];
    }
    if (tid >= 64 && tid < 68) xmr[tid - 64] = xm[(b * 1024 + l) * 4 + (tid - 64)];
    __syncthreads();
    int d = tid;
    float acc = 0.f;
    #pragma unroll
    for (int k = 0; k < 3; k++)
        for (int c = 0; c < 21; c++)
            acc += xr[k][c] * tokw[(d * 21 + c) * 3 + k];
    // positional embedding
    float div = __expf((float)(d & ~1) * (-9.210340371976184f / 256.0f));
    float arg = (float)l * div;
    acc += (d & 1) ? cosf(arg) : sinf(arg);
    #pragma unroll
    for (int t = 0; t < 4; t++) acc += xmr[t] * tembw[d * 4 + t];
    h[(size_t)blk * 256 + d] = acc;
    hbf[(size_t)blk * 256 + d] = f2b(acc);
}

// ---------------- MFMA bf16 GEMM: C[m,n] = sum_k A[m,k] * W[n,k] ----------------
// Wave per 16x16 output tile; direct global frag loads.
__global__ __launch_bounds__(256) void gemm_bf16_bf16(const ushort_t* __restrict__ A,
        const ushort_t* __restrict__ W, ushort_t* __restrict__ C,
        int M, int N, int K, int ldc) {
    int lane = threadIdx.x & 63;
    int wid = blockIdx.x * 4 + (threadIdx.x >> 6);
    int tiles_n = (N + 15) >> 4;
    int tile_m = wid / tiles_n, tile_n = wid - tile_m * tiles_n;
    if (tile_m * 16 >= M) return;
    int rr = lane & 15, quad = lane >> 4;
    int m = tile_m * 16 + rr;
    int n = tile_n * 16 + rr;
    bool nv = n < N;
    const ushort_t* arow = A + (size_t)m * K + quad * 8;
    const ushort_t* brow = W + (size_t)(nv ? n : N - 1) * K + quad * 8;
    f32x4 acc = {0.f, 0.f, 0.f, 0.f};
    for (int k = 0; k < K; k += 32) {
        short8 a = *(const short8*)(arow + k);
        short8 bb = *(const short8*)(brow + k);
        acc = __builtin_amdgcn_mfma_f32_16x16x32_bf16(a, bb, acc, 0, 0, 0);
    }
    if (nv) {
        int m0 = tile_m * 16 + quad * 4;
        #pragma unroll
        for (int i = 0; i < 4; i++) C[(size_t)(m0 + i) * ldc + n] = f2b(acc[i]);
    }
}

__global__ __launch_bounds__(256) void gemm_bf16_f32(const ushort_t* __restrict__ A,
        const ushort_t* __restrict__ W, float* __restrict__ C,
        int M, int N, int K, int ldc) {
    int lane = threadIdx.x & 63;
    int wid = blockIdx.x * 4 + (threadIdx.x >> 6);
    int tiles_n = (N + 15) >> 4;
    int tile_m = wid / tiles_n, tile_n = wid - tile_m * tiles_n;
    if (tile_m * 16 >= M) return;
    int rr = lane & 15, quad = lane >> 4;
    int m = tile_m * 16 + rr;
    int n = tile_n * 16 + rr;
    bool nv = n < N;
    const ushort_t* arow = A + (size_t)m * K + quad * 8;
    const ushort_t* brow = W + (size_t)(nv ? n : N - 1) * K + quad * 8;
    f32x4 acc = {0.f, 0.f, 0.f, 0.f};
    for (int k = 0; k < K; k += 32) {
        short8 a = *(const short8*)(arow + k);
        short8 bb = *(const short8*)(brow + k);
        acc = __builtin_amdgcn_mfma_f32_16x16x32_bf16(a, bb, acc, 0, 0, 0);
    }
    if (nv) {
        int m0 = tile_m * 16 + quad * 4;
        #pragma unroll
        for (int i = 0; i < 4; i++) C[(size_t)(m0 + i) * ldc + n] = acc[i];
    }
}

// ---------------- causal depthwise conv (DC=4) + bias + silu ----------------
__global__ __launch_bounds__(256) void conv_kernel(const ushort_t* __restrict__ zx,
        const float* __restrict__ cw, const float* __restrict__ cb,
        ushort_t* __restrict__ xc) {
    int idx = blockIdx.x * 256 + threadIdx.x;   // < 32*1024*640
    int ch = idx % 640;
    int r = idx / 640;
    int l = r & 1023, b = r >> 10;
    float acc = cb[ch];
    #pragma unroll
    for (int k = 0; k < 4; k++) {
        int ll = l - 3 + k;
        if (ll >= 0)
            acc += b2f(zx[(size_t)(b * 1024 + ll) * 1160 + 512 + ch]) * cw[ch * 4 + k];
    }
    xc[idx] = f2b(silu_f(acc));
}

// ---------------- dt = softplus(dt_raw + bias) ----------------
__global__ __launch_bounds__(256) void dt_kernel(const ushort_t* __restrict__ zx,
        const float* __restrict__ dtb, float* __restrict__ dts) {
    int idx = blockIdx.x * 256 + threadIdx.x;   // < 262144
    int r = idx >> 3, hh = idx & 7;
    float x = b2f(zx[(size_t)r * 1160 + 1152 + hh]) + dtb[hh];
    dts[idx] = (x > 20.f) ? x : log1pf(__expf(x));
}

// ---------------- SSD chunked scan: one block per (b, head) ----------------
__global__ __launch_bounds__(256) void ssd_kernel(const ushort_t* __restrict__ xc,
        const float* __restrict__ dts, const float* __restrict__ alog,
        const float* __restrict__ dsk, ushort_t* __restrict__ y) {
    int b = blockIdx.x >> 3, h = blockIdx.x & 7;
    float Ah = -__expf(alog[h]);
    float Dh = dsk[h];
    int tid = threadIdx.x;
    int q = tid >> 2;               // 0..63 (row / n-index)
    int c0 = (tid & 3) * 16;        // column block start

    __shared__ float Xr[64][64];        // raw xs [q][p]
    __shared__ float St[64][64];        // state transposed [n][p]
    __shared__ ushort_t Bs[64][66];     // B bf16 [q][n], pad 2
    __shared__ ushort_t Cs[64][66];     // C bf16 [q][n]; reused for G bf16 [q][s]
    __shared__ float acum[64], dtq[64], dec[64];
    __shared__ float adecay;

    for (int i = tid; i < 4096; i += 256) ((float*)St)[i] = 0.f;
    __syncthreads();

    for (int chk = 0; chk < 16; chk++) {
        int l0 = chk * 64;
        const ushort_t* xrow = xc + (size_t)(b * 1024 + l0 + q) * 640;
        #pragma unroll
        for (int j = 0; j < 16; j++) {
            Xr[q][c0 + j] = b2f(xrow[h * 64 + c0 + j]);
            Bs[q][c0 + j] = xrow[512 + c0 + j];
            Cs[q][c0 + j] = xrow[576 + c0 + j];
        }
        if (tid < 64) {
            float d = dts[(size_t)(b * 1024 + l0 + tid) * 8 + h];
            dtq[tid] = d;
            float a = d * Ah;
            #pragma unroll
            for (int off = 1; off < 64; off <<= 1) {
                float t = __shfl_up(a, off, 64);
                if (tid >= off) a += t;
            }
            acum[tid] = a;
            float tot = __shfl(a, 63, 64);
            dec[tid] = __expf(tot - a) * d;     // decay_states * dt
            if (tid == 0) adecay = __expf(tot); // chunk decay for state
        }
        __syncthreads();    // b1

        float out[16];
        #pragma unroll
        for (int j = 0; j < 16; j++) out[j] = 0.f;

        // Y_off = C @ S_prev^T   (out[q][p] += C[q][n] * St[n][p])
        for (int n = 0; n < 64; n++) {
            float cv = b2f(Cs[q][n]);
            const float4* sv = (const float4*)(&St[n][c0]);
            #pragma unroll
            for (int jj = 0; jj < 4; jj++) {
                float4 v = sv[jj];
                out[4 * jj + 0] += cv * v.x; out[4 * jj + 1] += cv * v.y;
                out[4 * jj + 2] += cv * v.z; out[4 * jj + 3] += cv * v.w;
            }
        }
        {
            float eq = __expf(acum[q]);
            #pragma unroll
            for (int j = 0; j < 16; j++) out[j] *= eq;
        }

        // G[q][s] = (C[q]·B[s]) * exp(acum[q]-acum[s]) * dt[s]   (s<=q)
        float g[16];
        #pragma unroll
        for (int i = 0; i < 16; i++) g[i] = 0.f;
        for (int n = 0; n < 64; n++) {
            float cv = b2f(Cs[q][n]);
            #pragma unroll
            for (int i = 0; i < 16; i++) g[i] += cv * b2f(Bs[c0 + i][n]);
        }
        {
            float aq = acum[q];
            #pragma unroll
            for (int i = 0; i < 16; i++) {
                int s = c0 + i;
                float e = (s <= q) ? __expf(aq - acum[s]) * dtq[s] : 0.f;
                g[i] *= e;
            }
        }
        __syncthreads();    // b2: all C reads done
        #pragma unroll
        for (int i = 0; i < 16; i++) Cs[q][c0 + i] = f2b(g[i]);
        __syncthreads();    // b3

        // Y_diag += G @ Xr
        for (int s = 0; s < 64; s++) {
            float gv = b2f(Cs[q][s]);
            const float4* xv = (const float4*)(&Xr[s][c0]);
            #pragma unroll
            for (int jj = 0; jj < 4; jj++) {
                float4 v = xv[jj];
                out[4 * jj + 0] += gv * v.x; out[4 * jj + 1] += gv * v.y;
                out[4 * jj + 2] += gv * v.z; out[4 * jj + 3] += gv * v.w;
            }
        }
        // write y = Y_diag + Y_off + D*xs
        {
            ushort_t* yrow = y + (size_t)(b * 1024 + l0 + q) * 512 + h * 64 + c0;
            #pragma unroll
            for (int j = 0; j < 16; j++) yrow[j] = f2b(out[j] + Dh * Xr[q][c0 + j]);
        }

        // states[n][p] = sum_q2 B[q2][n]*dec[q2] * Xr[q2][p]   (n = this thread's q)
        float sacc[16];
        #pragma unroll
        for (int j = 0; j < 16; j++) sacc[j] = 0.f;
        for (int q2 = 0; q2 < 64; q2++) {
            float bv = b2f(Bs[q2][q]) * dec[q2];
            const float4* xv = (const float4*)(&Xr[q2][c0]);
            #pragma unroll
            for (int jj = 0; jj < 4; jj++) {
                float4 v = xv[jj];
                sacc[4 * jj + 0] += bv * v.x; sacc[4 * jj + 1] += bv * v.y;
                sacc[4 * jj + 2] += bv * v.z; sacc[4 * jj + 3] += bv * v.w;
            }
        }
        __syncthreads();    // b4: all LDS reads of this chunk done
        {
            float ad = adecay;
            #pragma unroll
            for (int j = 0; j < 16; j++) St[q][c0 + j] = ad * St[q][c0 + j] + sacc[j];
        }
        __syncthreads();    // b5: state updated before next chunk
    }
}

// ---------------- gate: y = y*silu(z), RMSnorm * gw (in-place, bf16) ----------------
__global__ __launch_bounds__(256) void gate_kernel(const ushort_t* __restrict__ zx,
        ushort_t* __restrict__ y, const float* __restrict__ gw) {
    int r = blockIdx.x, tid = threadIdx.x;
    size_t zbase = (size_t)r * 1160;
    size_t ybase = (size_t)r * 512;
    float z0 = b2f(zx[zbase + tid]);
    float z1 = b2f(zx[zbase + tid + 256]);
    float v0 = b2f(y[ybase + tid]) * silu_f(z0);
    float v1 = b2f(y[ybase + tid + 256]) * silu_f(z1);
    float ss = v0 * v0 + v1 * v1;
    __shared__ float red[4];
    for (int o = 32; o > 0; o >>= 1) ss += __shfl_down(ss, o, 64);
    if ((tid & 63) == 0) red[tid >> 6] = ss;
    __syncthreads();
    float tot = red[0] + red[1] + red[2] + red[3];
    float rms = rsqrtf(tot * (1.f / 512.f) + 1e-5f);
    y[ybase + tid] = f2b(v0 * rms * gw[tid]);
    y[ybase + tid + 256] = f2b(v1 * rms * gw[tid + 256]);
}

// ---------------- residual + layernorm ----------------
__global__ __launch_bounds__(256) void resln_kernel(float* __restrict__ h,
        ushort_t* __restrict__ hbf, const float* __restrict__ yp,
        const float* __restrict__ g, const float* __restrict__ bb) {
    int r = blockIdx.x, tid = threadIdx.x;
    size_t base = (size_t)r * 256;
    float x = h[base + tid] + yp[base + tid];
    float s = x, s2 = x * x;
    __shared__ float r1[4], r2[4];
    for (int o = 32; o > 0; o >>= 1) { s += __shfl_down(s, o, 64); s2 += __shfl_down(s2, o, 64); }
    if ((tid & 63) == 0) { r1[tid >> 6] = s; r2[tid >> 6] = s2; }
    __syncthreads();
    float S = r1[0] + r1[1] + r1[2] + r1[3];
    float S2 = r2[0] + r2[1] + r2[2] + r2[3];
    float mu = S * (1.f / 256.f);
    float var = S2 * (1.f / 256.f) - mu * mu;
    float o = (x - mu) * rsqrtf(var + 1e-5f) * g[tid] + bb[tid];
    h[base + tid] = o;
    hbf[base + tid] = f2b(o);
}

// ---------------- head: out = (h @ head_w.T) * std + mean, last 192 steps ----------------
__global__ __launch_bounds__(256) void head_kernel(const float* __restrict__ h,
        const float* __restrict__ hw, const float* __restrict__ stdb,
        const float* __restrict__ meanb, float* __restrict__ out) {
    int blk = blockIdx.x;       // b*192 + t
    int b = blk / 192, t = blk - b * 192;
    int l = 832 + t;
    int tid = threadIdx.x;
    __shared__ float hr[256];
    hr[tid] = h[(size_t)(b * 1024 + l) * 256 + tid];
    __syncthreads();
    if (tid < 21) {
        float acc = 0.f;
        for (int k = 0; k < 256; k++) acc += hr[k] * hw[tid * 256 + k];
        out[(size_t)blk * 21 + tid] = acc * stdb[b * 21 + tid] + meanb[b * 21 + tid];
    }
}

extern "C" void kernel_launch(void* const* d_in, const int* in_sizes, int n_in,
                              void* d_out, int out_size, void* d_ws, size_t ws_size,
                              hipStream_t stream) {
    const float* x_enc  = (const float*)d_in[0];
    const float* x_mark = (const float*)d_in[1];
    const float* tokw   = (const float*)d_in[4];
    const float* tembw  = (const float*)d_in[5];
    const float* ln_g   = (const float*)d_in[6];
    const float* ln_b   = (const float*)d_in[7];
    const float* ipw    = (const float*)d_in[8];
    const float* cw     = (const float*)d_in[9];
    const float* cb     = (const float*)d_in[10];
    const float* dtb    = (const float*)d_in[11];
    const float* alog   = (const float*)d_in[12];
    const float* dsk    = (const float*)d_in[13];
    const float* gw     = (const float*)d_in[14];
    const float* opw    = (const float*)d_in[15];
    const float* hw     = (const float*)d_in[16];
    float* out = (float*)d_out;

    char* w = (char*)d_ws;
    size_t off = 0;
    auto alloc = [&](size_t bytes) -> void* {
        void* p = w + off;
        off += (bytes + 255) & ~(size_t)255;
        return p;
    };
    float* meanb  = (float*)alloc(672 * 4);
    float* stdb   = (float*)alloc(672 * 4);
    float* rstdb  = (float*)alloc(672 * 4);
    float* dts    = (float*)alloc((size_t)262144 * 4);
    float* hbuf   = (float*)alloc((size_t)8388608 * 4);
    ushort_t* hbf = (ushort_t*)alloc((size_t)8388608 * 2);
    ushort_t* zx  = (ushort_t*)alloc((size_t)38010880 * 2);   // 32768 x 1160 bf16
    ushort_t* xc  = (ushort_t*)alloc((size_t)20971520 * 2);   // 32768 x 640 bf16 (aliased by yproj later)
    ushort_t* ybuf= (ushort_t*)alloc((size_t)16777216 * 2);   // 32768 x 512 bf16
    ushort_t* wipb= (ushort_t*)alloc((size_t)1187840 * 2);    // in_proj_w bf16 (4x1160x256)
    ushort_t* wopb= (ushort_t*)alloc((size_t)524288 * 2);     // out_proj_w bf16 (4x256x512)
    float* yproj  = (float*)xc;                               // alias: xc dead when out_proj runs
    (void)ws_size; (void)in_sizes; (void)n_in; (void)out_size;

    stats_kernel<<<672, 256, 0, stream>>>(x_enc, meanb, stdb, rstdb);
    embed_kernel<<<32768, 256, 0, stream>>>(x_enc, x_mark, tokw, tembw, meanb, rstdb, hbuf, hbf);
    cvt_kernel<<<4640, 256, 0, stream>>>(ipw, wipb, 1187840);
    cvt_kernel<<<2048, 256, 0, stream>>>(opw, wopb, 524288);

    for (int layer = 0; layer < 4; layer++) {
        // in_proj: 32768x1160x256, tiles 2048x73 = 149504 waves -> 37376 blocks
        gemm_bf16_bf16<<<37376, 256, 0, stream>>>(hbf, wipb + (size_t)layer * 1160 * 256,
                                                  zx, 32768, 1160, 256, 1160);
        conv_kernel<<<81920, 256, 0, stream>>>(zx, cw + layer * 640 * 4, cb + layer * 640, xc);
        dt_kernel<<<1024, 256, 0, stream>>>(zx, dtb + layer * 8, dts);
        ssd_kernel<<<256, 256, 0, stream>>>(xc, dts, alog + layer * 8, dsk + layer * 8, ybuf);
        gate_kernel<<<32768, 256, 0, stream>>>(zx, ybuf, gw + layer * 512);
        // out_proj: 32768x256x512, tiles 2048x16 = 32768 waves -> 8192 blocks
        gemm_bf16_f32<<<8192, 256, 0, stream>>>(ybuf, wopb + (size_t)layer * 256 * 512,
                                                yproj, 32768, 256, 512, 256);
        resln_kernel<<<32768, 256, 0, stream>>>(hbuf, hbf, yproj, ln_g + layer * 256, ln_b + layer * 256);
    }

    head_kernel<<<6144, 256, 0, stream>>>(hbuf, hw, stdb, meanb, out);
}

// Round 4
// 1744.095 us; speedup vs baseline: 2.1644x; 2.1644x over previous
//
#include <hip/hip_runtime.h>
#include <hip/hip_bf16.h>

// Model: 4-layer Mamba2 TS model. B=32 L=1024 DM=256 DI=512 DST=64 NH=8 HD=64
// DC=4 Q=64 chunks=16 DIP=1160(pad 1216) CONVD=640 PRED=192 CO=21.
// I/O fp32. bf16 MFMA operands, fp32 accum.
// Workspace budget: 235.3 MB (round-3's 318 MB core-dumped; 207 MB proven OK).
// Key aliasing: xbuf (in_proj xBC+dt out, 46.1 MB) dies after conv+dt ->
// stbuf/acbuf (71.3 MB) reuse its region. yproj aliases xc.

typedef unsigned short ushort_t;
typedef unsigned int uint_t;
typedef __attribute__((ext_vector_type(8))) short short8;
typedef __attribute__((ext_vector_type(4))) float f32x4;

__device__ __forceinline__ float b2f(ushort_t u) {
    uint_t v = ((uint_t)u) << 16;
    return __builtin_bit_cast(float, v);
}
__device__ __forceinline__ ushort_t f2b(float f) {
    uint_t u = __builtin_bit_cast(uint_t, f);
    uint_t r = (u + 0x7FFFu + ((u >> 16) & 1u)) >> 16;
    return (ushort_t)r;
}
__device__ __forceinline__ float silu_f(float x) {
    return x / (1.f + __expf(-x));
}

// ---------------- weight converts ----------------
__global__ __launch_bounds__(256) void cvt_kernel(const float* __restrict__ in,
        ushort_t* __restrict__ out, int n) {
    int i = blockIdx.x * 256 + threadIdx.x;
    if (i < n) out[i] = f2b(in[i]);
}
// in_proj w: [4][1160][256] -> bf16 [4][1216][256], rows >=1160 zero
__global__ __launch_bounds__(256) void cvt_pad_ip(const float* __restrict__ in,
        ushort_t* __restrict__ out) {
    int i = blockIdx.x * 256 + threadIdx.x;     // < 4*1216*256
    if (i >= 4 * 1216 * 256) return;
    int layer = i / (1216 * 256);
    int rem = i - layer * 1216 * 256;
    int n = rem >> 8, k = rem & 255;
    out[i] = (n < 1160) ? f2b(in[(size_t)layer * 1160 * 256 + n * 256 + k]) : (ushort_t)0;
}

// ---------------- stats ----------------
__global__ __launch_bounds__(256) void stats_kernel(const float* __restrict__ xe,
        float* __restrict__ meanb, float* __restrict__ stdb, float* __restrict__ rstdb) {
    int bi = blockIdx.x;
    int b = bi / 21, c = bi - b * 21;
    int tid = threadIdx.x;
    float s = 0.f, s2 = 0.f;
    for (int l = tid; l < 1024; l += 256) {
        float v = xe[(b * 1024 + l) * 21 + c];
        s += v; s2 += v * v;
    }
    __shared__ float r1[4], r2[4];
    for (int o = 32; o > 0; o >>= 1) { s += __shfl_down(s, o, 64); s2 += __shfl_down(s2, o, 64); }
    if ((tid & 63) == 0) { r1[tid >> 6] = s; r2[tid >> 6] = s2; }
    __syncthreads();
    if (tid == 0) {
        float S = r1[0] + r1[1] + r1[2] + r1[3];
        float S2 = r2[0] + r2[1] + r2[2] + r2[3];
        float m = S * (1.f / 1024.f);
        float var = S2 * (1.f / 1024.f) - m * m;
        float sd = sqrtf(var + 1e-5f);
        meanb[bi] = m; stdb[bi] = sd; rstdb[bi] = 1.f / sd;
    }
}

// ---------------- embedding ----------------
__global__ __launch_bounds__(256) void embed_kernel(const float* __restrict__ xe,
        const float* __restrict__ xm, const float* __restrict__ tokw,
        const float* __restrict__ tembw, const float* __restrict__ meanb,
        const float* __restrict__ rstdb, float* __restrict__ h, ushort_t* __restrict__ hbf) {
    int blk = blockIdx.x;
    int b = blk >> 10, l = blk & 1023;
    int tid = threadIdx.x;
    __shared__ float xr[3][21];
    __shared__ float xmr[4];
    if (tid < 63) {
        int k = tid / 21, c = tid - k * 21;
        int ll = (l + k - 1 + 1024) & 1023;
        xr[k][c] = (xe[(b * 1024 + ll) * 21 + c] - meanb[b * 21 + c]) * rstdb[b * 21 + c];
    }
    if (tid >= 64 && tid < 68) xmr[tid - 64] = xm[(b * 1024 + l) * 4 + (tid - 64)];
    __syncthreads();
    int d = tid;
    float acc = 0.f;
    #pragma unroll
    for (int k = 0; k < 3; k++)
        for (int c = 0; c < 21; c++)
            acc += xr[k][c] * tokw[(d * 21 + c) * 3 + k];
    float div = __expf((float)(d & ~1) * (-9.210340371976184f / 256.0f));
    float arg = (float)l * div;
    acc += (d & 1) ? cosf(arg) : sinf(arg);
    #pragma unroll
    for (int t = 0; t < 4; t++) acc += xmr[t] * tembw[d * 4 + t];
    h[(size_t)blk * 256 + d] = acc;
    hbf[(size_t)blk * 256 + d] = f2b(acc);
}

// ---------------- in_proj GEMM: 64x64/wave, split store z|xBCdt ----------------
// A[32768x256] bf16, W[1216x256] bf16. tiles: 512 x 19.
__global__ __launch_bounds__(256) void gemm_ip(const ushort_t* __restrict__ A,
        const ushort_t* __restrict__ W, ushort_t* __restrict__ zbuf,
        ushort_t* __restrict__ xbuf) {
    int lane = threadIdx.x & 63;
    int wid = blockIdx.x * 4 + (threadIdx.x >> 6);
    int tm = wid / 19, tn = wid - tm * 19;
    int m0 = tm * 64, n0 = tn * 64;
    int rr = lane & 15, quad = lane >> 4;
    const ushort_t* ap = A + (size_t)(m0 + rr) * 256 + quad * 8;
    const ushort_t* wp = W + (size_t)(n0 + rr) * 256 + quad * 8;
    f32x4 acc[16];
    #pragma unroll
    for (int i = 0; i < 16; i++) acc[i] = (f32x4){0.f, 0.f, 0.f, 0.f};
    #pragma unroll
    for (int k = 0; k < 256; k += 32) {
        short8 a[4], bb[4];
        #pragma unroll
        for (int i = 0; i < 4; i++) a[i] = *(const short8*)(ap + (size_t)i * 16 * 256 + k);
        #pragma unroll
        for (int j = 0; j < 4; j++) bb[j] = *(const short8*)(wp + (size_t)j * 16 * 256 + k);
        #pragma unroll
        for (int i = 0; i < 4; i++)
            #pragma unroll
            for (int j = 0; j < 4; j++)
                acc[i * 4 + j] = __builtin_amdgcn_mfma_f32_16x16x32_bf16(a[i], bb[j], acc[i * 4 + j], 0, 0, 0);
    }
    #pragma unroll
    for (int i = 0; i < 4; i++) {
        int mrow = m0 + i * 16 + quad * 4;
        #pragma unroll
        for (int j = 0; j < 4; j++) {
            int n = n0 + j * 16 + rr;
            #pragma unroll
            for (int r2 = 0; r2 < 4; r2++) {
                ushort_t v = f2b(acc[i * 4 + j][r2]);
                if (tn < 8) zbuf[(size_t)(mrow + r2) * 512 + n] = v;
                else if (n < 1160) xbuf[(size_t)(mrow + r2) * 704 + (n - 512)] = v;
            }
        }
    }
}

// ---------------- causal depthwise conv + bias + silu ----------------
__global__ __launch_bounds__(256) void conv_kernel(const ushort_t* __restrict__ xbuf,
        const float* __restrict__ cw, const float* __restrict__ cb,
        ushort_t* __restrict__ xc) {
    int idx = blockIdx.x * 256 + threadIdx.x;   // < 32*1024*640
    int ch = idx % 640;
    int r = idx / 640;
    int l = r & 1023, b = r >> 10;
    float acc = cb[ch];
    #pragma unroll
    for (int k = 0; k < 4; k++) {
        int ll = l - 3 + k;
        if (ll >= 0)
            acc += b2f(xbuf[(size_t)(b * 1024 + ll) * 704 + ch]) * cw[ch * 4 + k];
    }
    xc[idx] = f2b(silu_f(acc));
}

// ---------------- dt = softplus(dt_raw + bias) ----------------
__global__ __launch_bounds__(256) void dt_kernel(const ushort_t* __restrict__ xbuf,
        const float* __restrict__ dtb, float* __restrict__ dts) {
    int idx = blockIdx.x * 256 + threadIdx.x;   // < 262144
    int r = idx >> 3, hh = idx & 7;
    float x = b2f(xbuf[(size_t)r * 704 + 640 + hh]) + dtb[hh];
    dts[idx] = (x > 20.f) ? x : log1pf(__expf(x));
}

// ---------------- SSD A: chunk states = (B*dec)^T @ X per (b,h,chunk) ----------------
__global__ __launch_bounds__(256) void ssd_stateA(const ushort_t* __restrict__ xc,
        const float* __restrict__ dts, const float* __restrict__ alog,
        float* __restrict__ stbuf, float* __restrict__ acbuf) {
    int idx = blockIdx.x;               // bh*16 + chunk
    int bh = idx >> 4, chunk = idx & 15;
    int b = bh >> 3, h = bh & 7;
    int l0 = chunk * 64;
    float Ah = -__expf(alog[h]);
    int tid = threadIdx.x;
    int q = tid >> 2, pb = (tid & 3) * 16;

    __shared__ ushort_t Bt[64][72], Xt[64][72];
    __shared__ float dec_s[64];

    const ushort_t* xrow = xc + (size_t)(b * 1024 + l0 + q) * 640;
    ushort_t bv[16], xv[16];
    *(short8*)&bv[0] = *(const short8*)(xrow + 512 + pb);
    *(short8*)&bv[8] = *(const short8*)(xrow + 512 + pb + 8);
    *(short8*)&xv[0] = *(const short8*)(xrow + h * 64 + pb);
    *(short8*)&xv[8] = *(const short8*)(xrow + h * 64 + pb + 8);
    #pragma unroll
    for (int j = 0; j < 16; j++) Xt[pb + j][q] = xv[j];

    if (tid < 64) {
        float d = dts[(size_t)(b * 1024 + l0 + tid) * 8 + h];
        float a = d * Ah;
        #pragma unroll
        for (int off = 1; off < 64; off <<= 1) {
            float t = __shfl_up(a, off, 64);
            if (tid >= off) a += t;
        }
        acbuf[(size_t)idx * 64 + tid] = a;
        float tot = __shfl(a, 63, 64);
        dec_s[tid] = __expf(tot - a) * d;
    }
    __syncthreads();
    {
        float dq = dec_s[q];
        #pragma unroll
        for (int j = 0; j < 16; j++) Bt[pb + j][q] = f2b(b2f(bv[j]) * dq);
    }
    __syncthreads();

    int w = tid >> 6, lane = tid & 63;
    int rr = lane & 15, quad = lane >> 4, qb = w * 16;
    f32x4 acc[4];
    #pragma unroll
    for (int t = 0; t < 4; t++) acc[t] = (f32x4){0.f, 0.f, 0.f, 0.f};
    #pragma unroll
    for (int ks = 0; ks < 2; ks++) {
        short8 a = *(const short8*)(&Bt[qb + rr][ks * 32 + quad * 8]);
        #pragma unroll
        for (int t = 0; t < 4; t++) {
            short8 bb = *(const short8*)(&Xt[t * 16 + rr][ks * 32 + quad * 8]);
            acc[t] = __builtin_amdgcn_mfma_f32_16x16x32_bf16(a, bb, acc[t], 0, 0, 0);
        }
    }
    float* sb = stbuf + (size_t)idx * 4096;
    #pragma unroll
    for (int t = 0; t < 4; t++) {
        int p = t * 16 + rr;
        #pragma unroll
        for (int r2 = 0; r2 < 4; r2++) {
            int nn = qb + quad * 4 + r2;
            sb[nn * 64 + p] = acc[t][r2];
        }
    }
}

// ---------------- SSD B: scan chunk states in place -> prefix states ----------------
__global__ __launch_bounds__(256) void ssd_scan(float* __restrict__ stbuf,
        const float* __restrict__ acbuf) {
    int bh = blockIdx.x, tid = threadIdx.x;
    float4 S[4];
    #pragma unroll
    for (int i = 0; i < 4; i++) S[i] = make_float4(0.f, 0.f, 0.f, 0.f);
    for (int c = 0; c < 16; c++) {
        float* p = stbuf + ((size_t)bh * 16 + c) * 4096 + tid * 16;
        float ad = __expf(acbuf[((size_t)bh * 16 + c) * 64 + 63]);
        #pragma unroll
        for (int i = 0; i < 4; i++) {
            float4 v = ((float4*)p)[i];
            ((float4*)p)[i] = S[i];
            S[i].x = ad * S[i].x + v.x; S[i].y = ad * S[i].y + v.y;
            S[i].z = ad * S[i].z + v.z; S[i].w = ad * S[i].w + v.w;
        }
    }
}

// ---------------- SSD C: y = Y_diag + Y_off + D*x -> bf16 ----------------
__global__ __launch_bounds__(256) void ssd_outBC(const ushort_t* __restrict__ xc,
        const float* __restrict__ dts, const float* __restrict__ alog,
        const float* __restrict__ dsk, const float* __restrict__ stbuf,
        ushort_t* __restrict__ ybuf) {
    int idx = blockIdx.x;
    int bh = idx >> 4, chunk = idx & 15;
    int b = bh >> 3, h = bh & 7;
    int l0 = chunk * 64;
    float Ah = -__expf(alog[h]);
    float Dh = dsk[h];
    int tid = threadIdx.x;
    int q = tid >> 2, pb = (tid & 3) * 16;

    __shared__ ushort_t Cs[64][72], Bs[64][72], Xt[64][72], Gs[64][72], Shi[64][72], Slo[64][72];
    __shared__ float acum_s[64], dtq_s[64], ea_s[64];

    const ushort_t* xrow = xc + (size_t)(b * 1024 + l0 + q) * 640;
    *(short8*)&Bs[q][pb]     = *(const short8*)(xrow + 512 + pb);
    *(short8*)&Bs[q][pb + 8] = *(const short8*)(xrow + 512 + pb + 8);
    *(short8*)&Cs[q][pb]     = *(const short8*)(xrow + 576 + pb);
    *(short8*)&Cs[q][pb + 8] = *(const short8*)(xrow + 576 + pb + 8);
    ushort_t xv[16];
    *(short8*)&xv[0] = *(const short8*)(xrow + h * 64 + pb);
    *(short8*)&xv[8] = *(const short8*)(xrow + h * 64 + pb + 8);
    #pragma unroll
    for (int j = 0; j < 16; j++) Xt[pb + j][q] = xv[j];
    {
        const float* sp = stbuf + (size_t)idx * 4096 + q * 64 + pb;
        #pragma unroll
        for (int j = 0; j < 16; j++) {
            float s = sp[j];
            ushort_t hi = f2b(s);
            Shi[pb + j][q] = hi;
            Slo[pb + j][q] = f2b(s - b2f(hi));
        }
    }
    if (tid < 64) {
        float d = dts[(size_t)(b * 1024 + l0 + tid) * 8 + h];
        dtq_s[tid] = d;
        float a = d * Ah;
        #pragma unroll
        for (int off = 1; off < 64; off <<= 1) {
            float t = __shfl_up(a, off, 64);
            if (tid >= off) a += t;
        }
        acum_s[tid] = a;
        ea_s[tid] = __expf(a);
    }
    __syncthreads();

    int w = tid >> 6, lane = tid & 63;
    int rr = lane & 15, quad = lane >> 4, qb = w * 16;

    // mm1: G = C.B^T masked -> Gs bf16
    {
        f32x4 g[4];
        #pragma unroll
        for (int t = 0; t < 4; t++) g[t] = (f32x4){0.f, 0.f, 0.f, 0.f};
        #pragma unroll
        for (int ks = 0; ks < 2; ks++) {
            short8 a = *(const short8*)(&Cs[qb + rr][ks * 32 + quad * 8]);
            #pragma unroll
            for (int t = 0; t < 4; t++) {
                short8 bb = *(const short8*)(&Bs[t * 16 + rr][ks * 32 + quad * 8]);
                g[t] = __builtin_amdgcn_mfma_f32_16x16x32_bf16(a, bb, g[t], 0, 0, 0);
            }
        }
        #pragma unroll
        for (int t = 0; t < 4; t++) {
            int s = t * 16 + rr;
            float as = acum_s[s], dss = dtq_s[s];
            #pragma unroll
            for (int r2 = 0; r2 < 4; r2++) {
                int qq = qb + quad * 4 + r2;
                float v = (s <= qq) ? g[t][r2] * __expf(acum_s[qq] - as) * dss : 0.f;
                Gs[qq][s] = f2b(v);
            }
        }
    }
    __syncthreads();

    // mm2: Y_diag = G@X ; Y_off = C@(Shi+Slo)
    f32x4 aD[4], aO[4];
    #pragma unroll
    for (int t = 0; t < 4; t++) { aD[t] = (f32x4){0.f,0.f,0.f,0.f}; aO[t] = (f32x4){0.f,0.f,0.f,0.f}; }
    #pragma unroll
    for (int ks = 0; ks < 2; ks++) {
        short8 ga = *(const short8*)(&Gs[qb + rr][ks * 32 + quad * 8]);
        short8 ca = *(const short8*)(&Cs[qb + rr][ks * 32 + quad * 8]);
        #pragma unroll
        for (int t = 0; t < 4; t++) {
            short8 xb = *(const short8*)(&Xt[t * 16 + rr][ks * 32 + quad * 8]);
            short8 sh = *(const short8*)(&Shi[t * 16 + rr][ks * 32 + quad * 8]);
            short8 sl = *(const short8*)(&Slo[t * 16 + rr][ks * 32 + quad * 8]);
            aD[t] = __builtin_amdgcn_mfma_f32_16x16x32_bf16(ga, xb, aD[t], 0, 0, 0);
            aO[t] = __builtin_amdgcn_mfma_f32_16x16x32_bf16(ca, sh, aO[t], 0, 0, 0);
            aO[t] = __builtin_amdgcn_mfma_f32_16x16x32_bf16(ca, sl, aO[t], 0, 0, 0);
        }
    }
    #pragma unroll
    for (int t = 0; t < 4; t++) {
        int p = t * 16 + rr;
        #pragma unroll
        for (int r2 = 0; r2 < 4; r2++) {
            int qq = qb + quad * 4 + r2;
            float y = aD[t][r2] + ea_s[qq] * aO[t][r2] + Dh * b2f(Xt[p][qq]);
            ybuf[(size_t)(b * 1024 + l0 + qq) * 512 + h * 64 + p] = f2b(y);
        }
    }
}

// ---------------- gate: y = y*silu(z), RMSnorm*gw (in-place bf16) ----------------
__global__ __launch_bounds__(256) void gate_kernel(const ushort_t* __restrict__ zbuf,
        ushort_t* __restrict__ ybuf, const float* __restrict__ gw) {
    int r = blockIdx.x, tid = threadIdx.x;
    size_t base = (size_t)r * 512;
    float z0 = b2f(zbuf[base + tid]);
    float z1 = b2f(zbuf[base + tid + 256]);
    float v0 = b2f(ybuf[base + tid]) * silu_f(z0);
    float v1 = b2f(ybuf[base + tid + 256]) * silu_f(z1);
    float ss = v0 * v0 + v1 * v1;
    __shared__ float red[4];
    for (int o = 32; o > 0; o >>= 1) ss += __shfl_down(ss, o, 64);
    if ((tid & 63) == 0) red[tid >> 6] = ss;
    __syncthreads();
    float tot = red[0] + red[1] + red[2] + red[3];
    float rms = rsqrtf(tot * (1.f / 512.f) + 1e-5f);
    ybuf[base + tid] = f2b(v0 * rms * gw[tid]);
    ybuf[base + tid + 256] = f2b(v1 * rms * gw[tid + 256]);
}

// ---------------- out_proj GEMM: 64x64/wave, fp32 out ----------------
// A[32768x512] bf16, W[512x512] bf16 -> C[32768x256] fp32. tiles 512 x 4... N=256: 512 x 4.
__global__ __launch_bounds__(256) void gemm_op(const ushort_t* __restrict__ A,
        const ushort_t* __restrict__ W, float* __restrict__ C) {
    int lane = threadIdx.x & 63;
    int wid = blockIdx.x * 4 + (threadIdx.x >> 6);
    int tm = wid >> 2, tn = wid & 3;            // tiles: 512 m x 4 n
    int m0 = tm * 64, n0 = tn * 64;
    int rr = lane & 15, quad = lane >> 4;
    const ushort_t* ap = A + (size_t)(m0 + rr) * 512 + quad * 8;
    const ushort_t* wp = W + (size_t)(n0 + rr) * 512 + quad * 8;
    f32x4 acc[16];
    #pragma unroll
    for (int i = 0; i < 16; i++) acc[i] = (f32x4){0.f, 0.f, 0.f, 0.f};
    #pragma unroll
    for (int k = 0; k < 512; k += 32) {
        short8 a[4], bb[4];
        #pragma unroll
        for (int i = 0; i < 4; i++) a[i] = *(const short8*)(ap + (size_t)i * 16 * 512 + k);
        #pragma unroll
        for (int j = 0; j < 4; j++) bb[j] = *(const short8*)(wp + (size_t)j * 16 * 512 + k);
        #pragma unroll
        for (int i = 0; i < 4; i++)
            #pragma unroll
            for (int j = 0; j < 4; j++)
                acc[i * 4 + j] = __builtin_amdgcn_mfma_f32_16x16x32_bf16(a[i], bb[j], acc[i * 4 + j], 0, 0, 0);
    }
    #pragma unroll
    for (int i = 0; i < 4; i++) {
        int mrow = m0 + i * 16 + quad * 4;
        #pragma unroll
        for (int j = 0; j < 4; j++) {
            int n = n0 + j * 16 + rr;
            #pragma unroll
            for (int r2 = 0; r2 < 4; r2++)
                C[(size_t)(mrow + r2) * 256 + n] = acc[i * 4 + j][r2];
        }
    }
}

// ---------------- residual + layernorm ----------------
__global__ __launch_bounds__(256) void resln_kernel(float* __restrict__ h,
        ushort_t* __restrict__ hbf, const float* __restrict__ yp,
        const float* __restrict__ g, const float* __restrict__ bb) {
    int r = blockIdx.x, tid = threadIdx.x;
    size_t base = (size_t)r * 256;
    float x = h[base + tid] + yp[base + tid];
    float s = x, s2 = x * x;
    __shared__ float r1[4], r2[4];
    for (int o = 32; o > 0; o >>= 1) { s += __shfl_down(s, o, 64); s2 += __shfl_down(s2, o, 64); }
    if ((tid & 63) == 0) { r1[tid >> 6] = s; r2[tid >> 6] = s2; }
    __syncthreads();
    float S = r1[0] + r1[1] + r1[2] + r1[3];
    float S2 = r2[0] + r2[1] + r2[2] + r2[3];
    float mu = S * (1.f / 256.f);
    float var = S2 * (1.f / 256.f) - mu * mu;
    float o = (x - mu) * rsqrtf(var + 1e-5f) * g[tid] + bb[tid];
    h[base + tid] = o;
    hbf[base + tid] = f2b(o);
}

// ---------------- head ----------------
__global__ __launch_bounds__(256) void head_kernel(const float* __restrict__ h,
        const float* __restrict__ hw, const float* __restrict__ stdb,
        const float* __restrict__ meanb, float* __restrict__ out) {
    int blk = blockIdx.x;       // b*192 + t
    int b = blk / 192, t = blk - b * 192;
    int l = 832 + t;
    int tid = threadIdx.x;
    __shared__ float hr[256];
    hr[tid] = h[(size_t)(b * 1024 + l) * 256 + tid];
    __syncthreads();
    if (tid < 21) {
        float acc = 0.f;
        for (int k = 0; k < 256; k++) acc += hr[k] * hw[tid * 256 + k];
        out[(size_t)blk * 21 + tid] = acc * stdb[b * 21 + tid] + meanb[b * 21 + tid];
    }
}

extern "C" void kernel_launch(void* const* d_in, const int* in_sizes, int n_in,
                              void* d_out, int out_size, void* d_ws, size_t ws_size,
                              hipStream_t stream) {
    const float* x_enc  = (const float*)d_in[0];
    const float* x_mark = (const float*)d_in[1];
    const float* tokw   = (const float*)d_in[4];
    const float* tembw  = (const float*)d_in[5];
    const float* ln_g   = (const float*)d_in[6];
    const float* ln_b   = (const float*)d_in[7];
    const float* ipw    = (const float*)d_in[8];
    const float* cw     = (const float*)d_in[9];
    const float* cb     = (const float*)d_in[10];
    const float* dtb    = (const float*)d_in[11];
    const float* alog   = (const float*)d_in[12];
    const float* dsk    = (const float*)d_in[13];
    const float* gw     = (const float*)d_in[14];
    const float* opw    = (const float*)d_in[15];
    const float* hw     = (const float*)d_in[16];
    float* out = (float*)d_out;

    char* w = (char*)d_ws;
    size_t off = 0;
    auto alloc = [&](size_t bytes) -> void* {
        void* p = w + off;
        off += (bytes + 255) & ~(size_t)255;
        return p;
    };
    float* meanb  = (float*)alloc(672 * 4);
    float* stdb   = (float*)alloc(672 * 4);
    float* rstdb  = (float*)alloc(672 * 4);
    float* dts    = (float*)alloc((size_t)262144 * 4);            // 1.05 MB
    float* hbuf   = (float*)alloc((size_t)8388608 * 4);           // 33.55 MB
    ushort_t* hbf = (ushort_t*)alloc((size_t)8388608 * 2);        // 16.78 MB
    ushort_t* zbuf= (ushort_t*)alloc((size_t)32768 * 512 * 2);    // 33.55 MB
    ushort_t* xc  = (ushort_t*)alloc((size_t)32768 * 640 * 2);    // 41.94 MB
    char* R       = (char*)alloc((size_t)71303168);               // 71.30 MB union
    ushort_t* ybuf= (ushort_t*)alloc((size_t)32768 * 512 * 2);    // 33.55 MB
    ushort_t* wipb= (ushort_t*)alloc((size_t)4 * 1216 * 256 * 2); // 2.49 MB
    ushort_t* wopb= (ushort_t*)alloc((size_t)4 * 256 * 512 * 2);  // 1.05 MB
    // region R aliases: xbuf (gemm_ip out) dies after conv+dt; stbuf/acbuf take over
    ushort_t* xbuf = (ushort_t*)R;                        // 32768 x 704 bf16 = 46.14 MB
    float* stbuf   = (float*)R;                           // 256*16*4096 fp32 = 67.11 MB
    float* acbuf   = (float*)(R + 67108864);              // 256*16*64 fp32 = 4.19 MB
    float* yproj   = (float*)xc;                          // alias: xc dead once gemm_op runs
    (void)ws_size; (void)in_sizes; (void)n_in; (void)out_size;
    // total ~235.3 MB

    stats_kernel<<<672, 256, 0, stream>>>(x_enc, meanb, stdb, rstdb);
    embed_kernel<<<32768, 256, 0, stream>>>(x_enc, x_mark, tokw, tembw, meanb, rstdb, hbuf, hbf);
    cvt_pad_ip<<<4864, 256, 0, stream>>>(ipw, wipb);
    cvt_kernel<<<2048, 256, 0, stream>>>(opw, wopb, 524288);

    for (int layer = 0; layer < 4; layer++) {
        // in_proj: 512x19 tiles = 9728 waves -> 2432 blocks
        gemm_ip<<<2432, 256, 0, stream>>>(hbf, wipb + (size_t)layer * 1216 * 256, zbuf, xbuf);
        conv_kernel<<<81920, 256, 0, stream>>>(xbuf, cw + layer * 640 * 4, cb + layer * 640, xc);
        dt_kernel<<<1024, 256, 0, stream>>>(xbuf, dtb + layer * 8, dts);
        // xbuf now dead -> stbuf/acbuf overwrite region R
        ssd_stateA<<<4096, 256, 0, stream>>>(xc, dts, alog + layer * 8, stbuf, acbuf);
        ssd_scan<<<256, 256, 0, stream>>>(stbuf, acbuf);
        ssd_outBC<<<4096, 256, 0, stream>>>(xc, dts, alog + layer * 8, dsk + layer * 8,
                                            stbuf, ybuf);
        gate_kernel<<<32768, 256, 0, stream>>>(zbuf, ybuf, gw + layer * 512);
        // out_proj: 512x4 tiles = 2048 waves -> 512 blocks
        gemm_op<<<512, 256, 0, stream>>>(ybuf, wopb + (size_t)layer * 256 * 512, yproj);
        resln_kernel<<<32768, 256, 0, stream>>>(hbuf, hbf, yproj,
                                                ln_g + layer * 256, ln_b + layer * 256);
    }

    head_kernel<<<6144, 256, 0, stream>>>(hbuf, hw, stdb, meanb, out);
}

// Round 5
// 1729.988 us; speedup vs baseline: 2.1820x; 1.0082x over previous
//
#include <hip/hip_runtime.h>
#include <hip/hip_bf16.h>

// Model: 4-layer Mamba2 TS model. B=32 L=1024 DM=256 DI=512 DST=64 NH=8 HD=64
// DC=4 Q=64 chunks=16 DIP=1160(pad 1216) CONVD=640 PRED=192 CO=21.
// I/O fp32. bf16 MFMA operands, fp32 accum.
// Workspace ~236.4 MB (235.3 proven OK round 4; 318 crashed round 3).
// R4->R5: pe table precomputed; embed LDS-tiled (was 260us latency-bound,
// 63 uncoalesced L2 loads/thread + 8.4M redundant sinf/cosf); scan 4-way split;
// conv vectorized 8ch/thread.

typedef unsigned short ushort_t;
typedef unsigned int uint_t;
typedef __attribute__((ext_vector_type(8))) short short8;
typedef __attribute__((ext_vector_type(4))) float f32x4;

__device__ __forceinline__ float b2f(ushort_t u) {
    uint_t v = ((uint_t)u) << 16;
    return __builtin_bit_cast(float, v);
}
__device__ __forceinline__ ushort_t f2b(float f) {
    uint_t u = __builtin_bit_cast(uint_t, f);
    uint_t r = (u + 0x7FFFu + ((u >> 16) & 1u)) >> 16;
    return (ushort_t)r;
}
__device__ __forceinline__ float silu_f(float x) {
    return x / (1.f + __expf(-x));
}

// ---------------- weight converts ----------------
__global__ __launch_bounds__(256) void cvt_kernel(const float* __restrict__ in,
        ushort_t* __restrict__ out, int n) {
    int i = blockIdx.x * 256 + threadIdx.x;
    if (i < n) out[i] = f2b(in[i]);
}
// in_proj w: [4][1160][256] -> bf16 [4][1216][256], rows >=1160 zero
__global__ __launch_bounds__(256) void cvt_pad_ip(const float* __restrict__ in,
        ushort_t* __restrict__ out) {
    int i = blockIdx.x * 256 + threadIdx.x;     // < 4*1216*256
    if (i >= 4 * 1216 * 256) return;
    int layer = i / (1216 * 256);
    int rem = i - layer * 1216 * 256;
    int n = rem >> 8, k = rem & 255;
    out[i] = (n < 1160) ? f2b(in[(size_t)layer * 1160 * 256 + n * 256 + k]) : (ushort_t)0;
}

// ---------------- pos-emb table: pe[l][d], computed once ----------------
__global__ __launch_bounds__(256) void pe_kernel(float* __restrict__ pe) {
    int l = blockIdx.x, d = threadIdx.x;
    float div = __expf((float)(d & ~1) * (-9.210340371976184f / 256.0f));
    float arg = (float)l * div;
    pe[l * 256 + d] = (d & 1) ? cosf(arg) : sinf(arg);
}

// ---------------- stats ----------------
__global__ __launch_bounds__(256) void stats_kernel(const float* __restrict__ xe,
        float* __restrict__ meanb, float* __restrict__ stdb, float* __restrict__ rstdb) {
    int bi = blockIdx.x;
    int b = bi / 21, c = bi - b * 21;
    int tid = threadIdx.x;
    float s = 0.f, s2 = 0.f;
    for (int l = tid; l < 1024; l += 256) {
        float v = xe[(b * 1024 + l) * 21 + c];
        s += v; s2 += v * v;
    }
    __shared__ float r1[4], r2[4];
    for (int o = 32; o > 0; o >>= 1) { s += __shfl_down(s, o, 64); s2 += __shfl_down(s2, o, 64); }
    if ((tid & 63) == 0) { r1[tid >> 6] = s; r2[tid >> 6] = s2; }
    __syncthreads();
    if (tid == 0) {
        float S = r1[0] + r1[1] + r1[2] + r1[3];
        float S2 = r2[0] + r2[1] + r2[2] + r2[3];
        float m = S * (1.f / 1024.f);
        float var = S2 * (1.f / 1024.f) - m * m;
        float sd = sqrtf(var + 1e-5f);
        meanb[bi] = m; stdb[bi] = sd; rstdb[bi] = 1.f / sd;
    }
}

// ---------------- embedding: LDS-tiled, 64 l-rows per block ----------------
__global__ __launch_bounds__(256) void embed2_kernel(const float* __restrict__ xe,
        const float* __restrict__ xm, const float* __restrict__ tokw,
        const float* __restrict__ tembw, const float* __restrict__ pe,
        const float* __restrict__ meanb, const float* __restrict__ rstdb,
        float* __restrict__ h, ushort_t* __restrict__ hbf) {
    int blk = blockIdx.x;               // b*16 + tile
    int b = blk >> 4, t = blk & 15;
    int l0 = t * 64;
    int tid = threadIdx.x;
    __shared__ float tw[16128];         // tokw, layout d*63 + c*3 + k (same as global)
    __shared__ float tb[1280];          // tembw, padded stride 5
    __shared__ float xw[66][21];        // normalized x window, row0 = l0-1 (wrap)
    __shared__ float xmw[64][4];
    __shared__ float mn[21], rs[21];
    if (tid < 21) { mn[tid] = meanb[b * 21 + tid]; rs[tid] = rstdb[b * 21 + tid]; }
    for (int i = tid; i < 16128; i += 256) tw[i] = tokw[i];
    if (tid < 256) {
        int d = tid;
        #pragma unroll
        for (int k = 0; k < 4; k++) tb[d * 5 + k] = tembw[d * 4 + k];
    }
    __syncthreads();
    for (int i = tid; i < 1386; i += 256) {
        int row = i / 21, c = i - row * 21;
        int gl = (l0 - 1 + row + 1024) & 1023;
        xw[row][c] = (xe[(size_t)(b * 1024 + gl) * 21 + c] - mn[c]) * rs[c];
    }
    {
        int row = tid >> 2, c = tid & 3;
        xmw[row][c] = xm[(size_t)(b * 1024 + l0 + row) * 4 + c];
    }
    __syncthreads();
    int d = tid;
    const float* twd = &tw[d * 63];
    for (int li = 0; li < 64; li++) {
        float a0 = 0.f, a1 = 0.f, a2 = 0.f;
        #pragma unroll
        for (int c = 0; c < 21; c++) {
            a0 += xw[li][c]     * twd[c * 3 + 0];
            a1 += xw[li + 1][c] * twd[c * 3 + 1];
            a2 += xw[li + 2][c] * twd[c * 3 + 2];
        }
        float acc = a0 + a1 + a2 + pe[(size_t)(l0 + li) * 256 + d];
        #pragma unroll
        for (int t2 = 0; t2 < 4; t2++) acc += xmw[li][t2] * tb[d * 5 + t2];
        size_t o = (size_t)(b * 1024 + l0 + li) * 256 + d;
        h[o] = acc;
        hbf[o] = f2b(acc);
    }
}

// ---------------- in_proj GEMM: 64x64/wave, split store z|xBCdt ----------------
// A[32768x256] bf16, W[1216x256] bf16. tiles: 512 x 19.
__global__ __launch_bounds__(256) void gemm_ip(const ushort_t* __restrict__ A,
        const ushort_t* __restrict__ W, ushort_t* __restrict__ zbuf,
        ushort_t* __restrict__ xbuf) {
    int lane = threadIdx.x & 63;
    int wid = blockIdx.x * 4 + (threadIdx.x >> 6);
    int tm = wid / 19, tn = wid - tm * 19;
    int m0 = tm * 64, n0 = tn * 64;
    int rr = lane & 15, quad = lane >> 4;
    const ushort_t* ap = A + (size_t)(m0 + rr) * 256 + quad * 8;
    const ushort_t* wp = W + (size_t)(n0 + rr) * 256 + quad * 8;
    f32x4 acc[16];
    #pragma unroll
    for (int i = 0; i < 16; i++) acc[i] = (f32x4){0.f, 0.f, 0.f, 0.f};
    #pragma unroll
    for (int k = 0; k < 256; k += 32) {
        short8 a[4], bb[4];
        #pragma unroll
        for (int i = 0; i < 4; i++) a[i] = *(const short8*)(ap + (size_t)i * 16 * 256 + k);
        #pragma unroll
        for (int j = 0; j < 4; j++) bb[j] = *(const short8*)(wp + (size_t)j * 16 * 256 + k);
        #pragma unroll
        for (int i = 0; i < 4; i++)
            #pragma unroll
            for (int j = 0; j < 4; j++)
                acc[i * 4 + j] = __builtin_amdgcn_mfma_f32_16x16x32_bf16(a[i], bb[j], acc[i * 4 + j], 0, 0, 0);
    }
    #pragma unroll
    for (int i = 0; i < 4; i++) {
        int mrow = m0 + i * 16 + quad * 4;
        #pragma unroll
        for (int j = 0; j < 4; j++) {
            int n = n0 + j * 16 + rr;
            #pragma unroll
            for (int r2 = 0; r2 < 4; r2++) {
                ushort_t v = f2b(acc[i * 4 + j][r2]);
                if (tn < 8) zbuf[(size_t)(mrow + r2) * 512 + n] = v;
                else if (n < 1160) xbuf[(size_t)(mrow + r2) * 704 + (n - 512)] = v;
            }
        }
    }
}

// ---------------- causal depthwise conv + bias + silu, 8 ch/thread ----------------
__global__ __launch_bounds__(256) void conv_kernel(const ushort_t* __restrict__ xbuf,
        const float* __restrict__ cw, const float* __restrict__ cb,
        ushort_t* __restrict__ xc) {
    int idx = blockIdx.x * 256 + threadIdx.x;   // < 32768*80
    int g = idx % 80;
    int r = idx / 80;
    int ch0 = g * 8;
    int l = r & 1023, b = r >> 10;
    float acc[8];
    #pragma unroll
    for (int j = 0; j < 8; j++) acc[j] = cb[ch0 + j];
    #pragma unroll
    for (int k = 0; k < 4; k++) {
        int ll = l - 3 + k;
        if (ll >= 0) {
            short8 xv = *(const short8*)(xbuf + (size_t)(b * 1024 + ll) * 704 + ch0);
            #pragma unroll
            for (int j = 0; j < 8; j++)
                acc[j] += b2f(((ushort_t*)&xv)[j]) * cw[(ch0 + j) * 4 + k];
        }
    }
    short8 o;
    #pragma unroll
    for (int j = 0; j < 8; j++) ((ushort_t*)&o)[j] = f2b(silu_f(acc[j]));
    *(short8*)(xc + (size_t)r * 640 + ch0) = o;
}

// ---------------- dt = softplus(dt_raw + bias) ----------------
__global__ __launch_bounds__(256) void dt_kernel(const ushort_t* __restrict__ xbuf,
        const float* __restrict__ dtb, float* __restrict__ dts) {
    int idx = blockIdx.x * 256 + threadIdx.x;   // < 262144
    int r = idx >> 3, hh = idx & 7;
    float x = b2f(xbuf[(size_t)r * 704 + 640 + hh]) + dtb[hh];
    dts[idx] = (x > 20.f) ? x : log1pf(__expf(x));
}

// ---------------- SSD A: chunk states = (B*dec)^T @ X per (b,h,chunk) ----------------
__global__ __launch_bounds__(256) void ssd_stateA(const ushort_t* __restrict__ xc,
        const float* __restrict__ dts, const float* __restrict__ alog,
        float* __restrict__ stbuf, float* __restrict__ acbuf) {
    int idx = blockIdx.x;               // bh*16 + chunk
    int bh = idx >> 4, chunk = idx & 15;
    int b = bh >> 3, h = bh & 7;
    int l0 = chunk * 64;
    float Ah = -__expf(alog[h]);
    int tid = threadIdx.x;
    int q = tid >> 2, pb = (tid & 3) * 16;

    __shared__ ushort_t Bt[64][72], Xt[64][72];
    __shared__ float dec_s[64];

    const ushort_t* xrow = xc + (size_t)(b * 1024 + l0 + q) * 640;
    ushort_t bv[16], xv[16];
    *(short8*)&bv[0] = *(const short8*)(xrow + 512 + pb);
    *(short8*)&bv[8] = *(const short8*)(xrow + 512 + pb + 8);
    *(short8*)&xv[0] = *(const short8*)(xrow + h * 64 + pb);
    *(short8*)&xv[8] = *(const short8*)(xrow + h * 64 + pb + 8);
    #pragma unroll
    for (int j = 0; j < 16; j++) Xt[pb + j][q] = xv[j];

    if (tid < 64) {
        float d = dts[(size_t)(b * 1024 + l0 + tid) * 8 + h];
        float a = d * Ah;
        #pragma unroll
        for (int off = 1; off < 64; off <<= 1) {
            float t = __shfl_up(a, off, 64);
            if (tid >= off) a += t;
        }
        acbuf[(size_t)idx * 64 + tid] = a;
        float tot = __shfl(a, 63, 64);
        dec_s[tid] = __expf(tot - a) * d;
    }
    __syncthreads();
    {
        float dq = dec_s[q];
        #pragma unroll
        for (int j = 0; j < 16; j++) Bt[pb + j][q] = f2b(b2f(bv[j]) * dq);
    }
    __syncthreads();

    int w = tid >> 6, lane = tid & 63;
    int rr = lane & 15, quad = lane >> 4, qb = w * 16;
    f32x4 acc[4];
    #pragma unroll
    for (int t = 0; t < 4; t++) acc[t] = (f32x4){0.f, 0.f, 0.f, 0.f};
    #pragma unroll
    for (int ks = 0; ks < 2; ks++) {
        short8 a = *(const short8*)(&Bt[qb + rr][ks * 32 + quad * 8]);
        #pragma unroll
        for (int t = 0; t < 4; t++) {
            short8 bb = *(const short8*)(&Xt[t * 16 + rr][ks * 32 + quad * 8]);
            acc[t] = __builtin_amdgcn_mfma_f32_16x16x32_bf16(a, bb, acc[t], 0, 0, 0);
        }
    }
    float* sb = stbuf + (size_t)idx * 4096;
    #pragma unroll
    for (int t = 0; t < 4; t++) {
        int p = t * 16 + rr;
        #pragma unroll
        for (int r2 = 0; r2 < 4; r2++) {
            int nn = qb + quad * 4 + r2;
            sb[nn * 64 + p] = acc[t][r2];
        }
    }
}

// ---------------- SSD B: scan chunk states in place (4-way split) ----------------
__global__ __launch_bounds__(256) void ssd_scan(float* __restrict__ stbuf,
        const float* __restrict__ acbuf) {
    int bh = blockIdx.x >> 2, sl = blockIdx.x & 3;
    int tid = threadIdx.x;
    size_t boff = (size_t)sl * 1024 + tid * 4;
    float4 S = make_float4(0.f, 0.f, 0.f, 0.f);
    for (int c = 0; c < 16; c++) {
        float* p = stbuf + ((size_t)bh * 16 + c) * 4096 + boff;
        float ad = __expf(acbuf[((size_t)bh * 16 + c) * 64 + 63]);
        float4 v = *(float4*)p;
        *(float4*)p = S;
        S.x = ad * S.x + v.x; S.y = ad * S.y + v.y;
        S.z = ad * S.z + v.z; S.w = ad * S.w + v.w;
    }
}

// ---------------- SSD C: y = Y_diag + Y_off + D*x -> bf16 ----------------
__global__ __launch_bounds__(256) void ssd_outBC(const ushort_t* __restrict__ xc,
        const float* __restrict__ dts, const float* __restrict__ alog,
        const float* __restrict__ dsk, const float* __restrict__ stbuf,
        ushort_t* __restrict__ ybuf) {
    int idx = blockIdx.x;
    int bh = idx >> 4, chunk = idx & 15;
    int b = bh >> 3, h = bh & 7;
    int l0 = chunk * 64;
    float Ah = -__expf(alog[h]);
    float Dh = dsk[h];
    int tid = threadIdx.x;
    int q = tid >> 2, pb = (tid & 3) * 16;

    __shared__ ushort_t Cs[64][72], Bs[64][72], Xt[64][72], Gs[64][72], Shi[64][72], Slo[64][72];
    __shared__ float acum_s[64], dtq_s[64], ea_s[64];

    const ushort_t* xrow = xc + (size_t)(b * 1024 + l0 + q) * 640;
    *(short8*)&Bs[q][pb]     = *(const short8*)(xrow + 512 + pb);
    *(short8*)&Bs[q][pb + 8] = *(const short8*)(xrow + 512 + pb + 8);
    *(short8*)&Cs[q][pb]     = *(const short8*)(xrow + 576 + pb);
    *(short8*)&Cs[q][pb + 8] = *(const short8*)(xrow + 576 + pb + 8);
    ushort_t xv[16];
    *(short8*)&xv[0] = *(const short8*)(xrow + h * 64 + pb);
    *(short8*)&xv[8] = *(const short8*)(xrow + h * 64 + pb + 8);
    #pragma unroll
    for (int j = 0; j < 16; j++) Xt[pb + j][q] = xv[j];
    {
        const float* sp = stbuf + (size_t)idx * 4096 + q * 64 + pb;
        #pragma unroll
        for (int j = 0; j < 16; j++) {
            float s = sp[j];
            ushort_t hi = f2b(s);
            Shi[pb + j][q] = hi;
            Slo[pb + j][q] = f2b(s - b2f(hi));
        }
    }
    if (tid < 64) {
        float d = dts[(size_t)(b * 1024 + l0 + tid) * 8 + h];
        dtq_s[tid] = d;
        float a = d * Ah;
        #pragma unroll
        for (int off = 1; off < 64; off <<= 1) {
            float t = __shfl_up(a, off, 64);
            if (tid >= off) a += t;
        }
        acum_s[tid] = a;
        ea_s[tid] = __expf(a);
    }
    __syncthreads();

    int w = tid >> 6, lane = tid & 63;
    int rr = lane & 15, quad = lane >> 4, qb = w * 16;

    // mm1: G = C.B^T masked -> Gs bf16
    {
        f32x4 g[4];
        #pragma unroll
        for (int t = 0; t < 4; t++) g[t] = (f32x4){0.f, 0.f, 0.f, 0.f};
        #pragma unroll
        for (int ks = 0; ks < 2; ks++) {
            short8 a = *(const short8*)(&Cs[qb + rr][ks * 32 + quad * 8]);
            #pragma unroll
            for (int t = 0; t < 4; t++) {
                short8 bb = *(const short8*)(&Bs[t * 16 + rr][ks * 32 + quad * 8]);
                g[t] = __builtin_amdgcn_mfma_f32_16x16x32_bf16(a, bb, g[t], 0, 0, 0);
            }
        }
        #pragma unroll
        for (int t = 0; t < 4; t++) {
            int s = t * 16 + rr;
            float as = acum_s[s], dss = dtq_s[s];
            #pragma unroll
            for (int r2 = 0; r2 < 4; r2++) {
                int qq = qb + quad * 4 + r2;
                float v = (s <= qq) ? g[t][r2] * __expf(acum_s[qq] - as) * dss : 0.f;
                Gs[qq][s] = f2b(v);
            }
        }
    }
    __syncthreads();

    // mm2: Y_diag = G@X ; Y_off = C@(Shi+Slo)
    f32x4 aD[4], aO[4];
    #pragma unroll
    for (int t = 0; t < 4; t++) { aD[t] = (f32x4){0.f,0.f,0.f,0.f}; aO[t] = (f32x4){0.f,0.f,0.f,0.f}; }
    #pragma unroll
    for (int ks = 0; ks < 2; ks++) {
        short8 ga = *(const short8*)(&Gs[qb + rr][ks * 32 + quad * 8]);
        short8 ca = *(const short8*)(&Cs[qb + rr][ks * 32 + quad * 8]);
        #pragma unroll
        for (int t = 0; t < 4; t++) {
            short8 xb = *(const short8*)(&Xt[t * 16 + rr][ks * 32 + quad * 8]);
            short8 sh = *(const short8*)(&Shi[t * 16 + rr][ks * 32 + quad * 8]);
            short8 sl = *(const short8*)(&Slo[t * 16 + rr][ks * 32 + quad * 8]);
            aD[t] = __builtin_amdgcn_mfma_f32_16x16x32_bf16(ga, xb, aD[t], 0, 0, 0);
            aO[t] = __builtin_amdgcn_mfma_f32_16x16x32_bf16(ca, sh, aO[t], 0, 0, 0);
            aO[t] = __builtin_amdgcn_mfma_f32_16x16x32_bf16(ca, sl, aO[t], 0, 0, 0);
        }
    }
    #pragma unroll
    for (int t = 0; t < 4; t++) {
        int p = t * 16 + rr;
        #pragma unroll
        for (int r2 = 0; r2 < 4; r2++) {
            int qq = qb + quad * 4 + r2;
            float y = aD[t][r2] + ea_s[qq] * aO[t][r2] + Dh * b2f(Xt[p][qq]);
            ybuf[(size_t)(b * 1024 + l0 + qq) * 512 + h * 64 + p] = f2b(y);
        }
    }
}

// ---------------- gate: y = y*silu(z), RMSnorm*gw (in-place bf16) ----------------
__global__ __launch_bounds__(256) void gate_kernel(const ushort_t* __restrict__ zbuf,
        ushort_t* __restrict__ ybuf, const float* __restrict__ gw) {
    int r = blockIdx.x, tid = threadIdx.x;
    size_t base = (size_t)r * 512;
    float z0 = b2f(zbuf[base + tid]);
    float z1 = b2f(zbuf[base + tid + 256]);
    float v0 = b2f(ybuf[base + tid]) * silu_f(z0);
    float v1 = b2f(ybuf[base + tid + 256]) * silu_f(z1);
    float ss = v0 * v0 + v1 * v1;
    __shared__ float red[4];
    for (int o = 32; o > 0; o >>= 1) ss += __shfl_down(ss, o, 64);
    if ((tid & 63) == 0) red[tid >> 6] = ss;
    __syncthreads();
    float tot = red[0] + red[1] + red[2] + red[3];
    float rms = rsqrtf(tot * (1.f / 512.f) + 1e-5f);
    ybuf[base + tid] = f2b(v0 * rms * gw[tid]);
    ybuf[base + tid + 256] = f2b(v1 * rms * gw[tid + 256]);
}

// ---------------- out_proj GEMM: 64x64/wave, fp32 out ----------------
__global__ __launch_bounds__(256) void gemm_op(const ushort_t* __restrict__ A,
        const ushort_t* __restrict__ W, float* __restrict__ C) {
    int lane = threadIdx.x & 63;
    int wid = blockIdx.x * 4 + (threadIdx.x >> 6);
    int tm = wid >> 2, tn = wid & 3;            // tiles: 512 m x 4 n
    int m0 = tm * 64, n0 = tn * 64;
    int rr = lane & 15, quad = lane >> 4;
    const ushort_t* ap = A + (size_t)(m0 + rr) * 512 + quad * 8;
    const ushort_t* wp = W + (size_t)(n0 + rr) * 512 + quad * 8;
    f32x4 acc[16];
    #pragma unroll
    for (int i = 0; i < 16; i++) acc[i] = (f32x4){0.f, 0.f, 0.f, 0.f};
    #pragma unroll
    for (int k = 0; k < 512; k += 32) {
        short8 a[4], bb[4];
        #pragma unroll
        for (int i = 0; i < 4; i++) a[i] = *(const short8*)(ap + (size_t)i * 16 * 512 + k);
        #pragma unroll
        for (int j = 0; j < 4; j++) bb[j] = *(const short8*)(wp + (size_t)j * 16 * 512 + k);
        #pragma unroll
        for (int i = 0; i < 4; i++)
            #pragma unroll
            for (int j = 0; j < 4; j++)
                acc[i * 4 + j] = __builtin_amdgcn_mfma_f32_16x16x32_bf16(a[i], bb[j], acc[i * 4 + j], 0, 0, 0);
    }
    #pragma unroll
    for (int i = 0; i < 4; i++) {
        int mrow = m0 + i * 16 + quad * 4;
        #pragma unroll
        for (int j = 0; j < 4; j++) {
            int n = n0 + j * 16 + rr;
            #pragma unroll
            for (int r2 = 0; r2 < 4; r2++)
                C[(size_t)(mrow + r2) * 256 + n] = acc[i * 4 + j][r2];
        }
    }
}

// ---------------- residual + layernorm ----------------
__global__ __launch_bounds__(256) void resln_kernel(float* __restrict__ h,
        ushort_t* __restrict__ hbf, const float* __restrict__ yp,
        const float* __restrict__ g, const float* __restrict__ bb) {
    int r = blockIdx.x, tid = threadIdx.x;
    size_t base = (size_t)r * 256;
    float x = h[base + tid] + yp[base + tid];
    float s = x, s2 = x * x;
    __shared__ float r1[4], r2[4];
    for (int o = 32; o > 0; o >>= 1) { s += __shfl_down(s, o, 64); s2 += __shfl_down(s2, o, 64); }
    if ((tid & 63) == 0) { r1[tid >> 6] = s; r2[tid >> 6] = s2; }
    __syncthreads();
    float S = r1[0] + r1[1] + r1[2] + r1[3];
    float S2 = r2[0] + r2[1] + r2[2] + r2[3];
    float mu = S * (1.f / 256.f);
    float var = S2 * (1.f / 256.f) - mu * mu;
    float o = (x - mu) * rsqrtf(var + 1e-5f) * g[tid] + bb[tid];
    h[base + tid] = o;
    hbf[base + tid] = f2b(o);
}

// ---------------- head ----------------
__global__ __launch_bounds__(256) void head_kernel(const float* __restrict__ h,
        const float* __restrict__ hw, const float* __restrict__ stdb,
        const float* __restrict__ meanb, float* __restrict__ out) {
    int blk = blockIdx.x;       // b*192 + t
    int b = blk / 192, t = blk - b * 192;
    int l = 832 + t;
    int tid = threadIdx.x;
    __shared__ float hr[256];
    hr[tid] = h[(size_t)(b * 1024 + l) * 256 + tid];
    __syncthreads();
    if (tid < 21) {
        float acc = 0.f;
        for (int k = 0; k < 256; k++) acc += hr[k] * hw[tid * 256 + k];
        out[(size_t)blk * 21 + tid] = acc * stdb[b * 21 + tid] + meanb[b * 21 + tid];
    }
}

extern "C" void kernel_launch(void* const* d_in, const int* in_sizes, int n_in,
                              void* d_out, int out_size, void* d_ws, size_t ws_size,
                              hipStream_t stream) {
    const float* x_enc  = (const float*)d_in[0];
    const float* x_mark = (const float*)d_in[1];
    const float* tokw   = (const float*)d_in[4];
    const float* tembw  = (const float*)d_in[5];
    const float* ln_g   = (const float*)d_in[6];
    const float* ln_b   = (const float*)d_in[7];
    const float* ipw    = (const float*)d_in[8];
    const float* cw     = (const float*)d_in[9];
    const float* cb     = (const float*)d_in[10];
    const float* dtb    = (const float*)d_in[11];
    const float* alog   = (const float*)d_in[12];
    const float* dsk    = (const float*)d_in[13];
    const float* gw     = (const float*)d_in[14];
    const float* opw    = (const float*)d_in[15];
    const float* hw     = (const float*)d_in[16];
    float* out = (float*)d_out;

    char* w = (char*)d_ws;
    size_t off = 0;
    auto alloc = [&](size_t bytes) -> void* {
        void* p = w + off;
        off += (bytes + 255) & ~(size_t)255;
        return p;
    };
    float* meanb  = (float*)alloc(672 * 4);
    float* stdb   = (float*)alloc(672 * 4);
    float* rstdb  = (float*)alloc(672 * 4);
    float* dts    = (float*)alloc((size_t)262144 * 4);            // 1.05 MB
    float* pebuf  = (float*)alloc((size_t)262144 * 4);            // 1.05 MB
    float* hbuf   = (float*)alloc((size_t)8388608 * 4);           // 33.55 MB
    ushort_t* hbf = (ushort_t*)alloc((size_t)8388608 * 2);        // 16.78 MB
    ushort_t* zbuf= (ushort_t*)alloc((size_t)32768 * 512 * 2);    // 33.55 MB
    ushort_t* xc  = (ushort_t*)alloc((size_t)32768 * 640 * 2);    // 41.94 MB
    char* R       = (char*)alloc((size_t)71303168);               // 71.30 MB union
    ushort_t* ybuf= (ushort_t*)alloc((size_t)32768 * 512 * 2);    // 33.55 MB
    ushort_t* wipb= (ushort_t*)alloc((size_t)4 * 1216 * 256 * 2); // 2.49 MB
    ushort_t* wopb= (ushort_t*)alloc((size_t)4 * 256 * 512 * 2);  // 1.05 MB
    // region R aliases: xbuf (gemm_ip out) dies after conv+dt; stbuf/acbuf take over
    ushort_t* xbuf = (ushort_t*)R;                        // 32768 x 704 bf16 = 46.14 MB
    float* stbuf   = (float*)R;                           // 256*16*4096 fp32 = 67.11 MB
    float* acbuf   = (float*)(R + 67108864);              // 256*16*64 fp32 = 4.19 MB
    float* yproj   = (float*)xc;                          // alias: xc dead once gemm_op runs
    (void)ws_size; (void)in_sizes; (void)n_in; (void)out_size;
    // total ~236.4 MB

    stats_kernel<<<672, 256, 0, stream>>>(x_enc, meanb, stdb, rstdb);
    pe_kernel<<<1024, 256, 0, stream>>>(pebuf);
    cvt_pad_ip<<<4864, 256, 0, stream>>>(ipw, wipb);
    cvt_kernel<<<2048, 256, 0, stream>>>(opw, wopb, 524288);
    embed2_kernel<<<512, 256, 0, stream>>>(x_enc, x_mark, tokw, tembw, pebuf,
                                           meanb, rstdb, hbuf, hbf);

    for (int layer = 0; layer < 4; layer++) {
        // in_proj: 512x19 tiles = 9728 waves -> 2432 blocks
        gemm_ip<<<2432, 256, 0, stream>>>(hbf, wipb + (size_t)layer * 1216 * 256, zbuf, xbuf);
        conv_kernel<<<10240, 256, 0, stream>>>(xbuf, cw + layer * 640 * 4, cb + layer * 640, xc);
        dt_kernel<<<1024, 256, 0, stream>>>(xbuf, dtb + layer * 8, dts);
        // xbuf now dead -> stbuf/acbuf overwrite region R
        ssd_stateA<<<4096, 256, 0, stream>>>(xc, dts, alog + layer * 8, stbuf, acbuf);
        ssd_scan<<<1024, 256, 0, stream>>>(stbuf, acbuf);
        ssd_outBC<<<4096, 256, 0, stream>>>(xc, dts, alog + layer * 8, dsk + layer * 8,
                                            stbuf, ybuf);
        gate_kernel<<<32768, 256, 0, stream>>>(zbuf, ybuf, gw + layer * 512);
        // out_proj: 512x4 tiles = 2048 waves -> 512 blocks
        gemm_op<<<512, 256, 0, stream>>>(ybuf, wopb + (size_t)layer * 256 * 512, yproj);
        resln_kernel<<<32768, 256, 0, stream>>>(hbuf, hbf, yproj,
                                                ln_g + layer * 256, ln_b + layer * 256);
    }

    head_kernel<<<6144, 256, 0, stream>>>(hbuf, hw, stdb, meanb, out);
}

// Round 6
// 1196.574 us; speedup vs baseline: 3.1547x; 1.4458x over previous
//
#include <hip/hip_runtime.h>
#include <hip/hip_bf16.h>

// Model: 4-layer Mamba2 TS model. B=32 L=1024 DM=256 DI=512 DST=64 NH=8 HD=64
// DC=4 Q=64 chunks=16 DIP=1160(pad 1216) CONVD=640 PRED=192 CO=21.
// I/O fp32. bf16 MFMA operands, fp32 accum. WS ~236.4 MB (<~256 limit).
// R5->R6: conv rewritten (cwt[k][640] transposed weights in regs via float4,
// 4-l blocking for x-row reuse; R5's 32 scalar stride-32B cw loads were
// L1-fragmentation-bound at 153us/9% VALU). embed rewritten (tokw in 63 regs,
// sliding-window; R5 version had 76KB static LDS -> 1 block/CU + 4032 scalar
// LDS reads/thread). Both keep exact fp32 accumulation order.

typedef unsigned short ushort_t;
typedef unsigned int uint_t;
typedef __attribute__((ext_vector_type(8))) short short8;
typedef __attribute__((ext_vector_type(4))) float f32x4;

__device__ __forceinline__ float b2f(ushort_t u) {
    uint_t v = ((uint_t)u) << 16;
    return __builtin_bit_cast(float, v);
}
__device__ __forceinline__ ushort_t f2b(float f) {
    uint_t u = __builtin_bit_cast(uint_t, f);
    uint_t r = (u + 0x7FFFu + ((u >> 16) & 1u)) >> 16;
    return (ushort_t)r;
}
__device__ __forceinline__ float silu_f(float x) {
    return x / (1.f + __expf(-x));
}

// ---------------- weight converts ----------------
__global__ __launch_bounds__(256) void cvt_kernel(const float* __restrict__ in,
        ushort_t* __restrict__ out, int n) {
    int i = blockIdx.x * 256 + threadIdx.x;
    if (i < n) out[i] = f2b(in[i]);
}
// in_proj w: [4][1160][256] -> bf16 [4][1216][256], rows >=1160 zero
__global__ __launch_bounds__(256) void cvt_pad_ip(const float* __restrict__ in,
        ushort_t* __restrict__ out) {
    int i = blockIdx.x * 256 + threadIdx.x;     // < 4*1216*256
    if (i >= 4 * 1216 * 256) return;
    int layer = i / (1216 * 256);
    int rem = i - layer * 1216 * 256;
    int n = rem >> 8, k = rem & 255;
    out[i] = (n < 1160) ? f2b(in[(size_t)layer * 1160 * 256 + n * 256 + k]) : (ushort_t)0;
}
// conv w: [4][640][4] -> [4][4][640] fp32 transpose
__global__ __launch_bounds__(256) void cvt_convw(const float* __restrict__ in,
        float* __restrict__ out) {
    int i = blockIdx.x * 256 + threadIdx.x;     // < 4*2560
    if (i >= 10240) return;
    int layer = i / 2560;
    int rem = i - layer * 2560;
    int k = rem / 640, ch = rem - k * 640;
    out[i] = in[layer * 2560 + ch * 4 + k];
}

// ---------------- pos-emb table: pe[l][d], computed once ----------------
__global__ __launch_bounds__(256) void pe_kernel(float* __restrict__ pe) {
    int l = blockIdx.x, d = threadIdx.x;
    float div = __expf((float)(d & ~1) * (-9.210340371976184f / 256.0f));
    float arg = (float)l * div;
    pe[l * 256 + d] = (d & 1) ? cosf(arg) : sinf(arg);
}

// ---------------- stats ----------------
__global__ __launch_bounds__(256) void stats_kernel(const float* __restrict__ xe,
        float* __restrict__ meanb, float* __restrict__ stdb, float* __restrict__ rstdb) {
    int bi = blockIdx.x;
    int b = bi / 21, c = bi - b * 21;
    int tid = threadIdx.x;
    float s = 0.f, s2 = 0.f;
    for (int l = tid; l < 1024; l += 256) {
        float v = xe[(b * 1024 + l) * 21 + c];
        s += v; s2 += v * v;
    }
    __shared__ float r1[4], r2[4];
    for (int o = 32; o > 0; o >>= 1) { s += __shfl_down(s, o, 64); s2 += __shfl_down(s2, o, 64); }
    if ((tid & 63) == 0) { r1[tid >> 6] = s; r2[tid >> 6] = s2; }
    __syncthreads();
    if (tid == 0) {
        float S = r1[0] + r1[1] + r1[2] + r1[3];
        float S2 = r2[0] + r2[1] + r2[2] + r2[3];
        float m = S * (1.f / 1024.f);
        float var = S2 * (1.f / 1024.f) - m * m;
        float sd = sqrtf(var + 1e-5f);
        meanb[bi] = m; stdb[bi] = sd; rstdb[bi] = 1.f / sd;
    }
}

// ---------------- embedding: sliding-window, tokw in registers ----------------
// out[b,l,d] = sum_{c,k} xw[l+k-1][c]*tokw[d,c,k] + pe[l,d] + sum_t xm[l,t]*tembw[d,t]
__global__ __launch_bounds__(256) void embed3_kernel(const float* __restrict__ xe,
        const float* __restrict__ xm, const float* __restrict__ tokw,
        const float* __restrict__ tembw, const float* __restrict__ pe,
        const float* __restrict__ meanb, const float* __restrict__ rstdb,
        float* __restrict__ h, ushort_t* __restrict__ hbf) {
    int blk = blockIdx.x;               // b*16 + tile
    int b = blk >> 4, t = blk & 15;
    int l0 = t * 64;
    int tid = threadIdx.x;              // = d
    __shared__ float xw[66][22];        // normalized x window, row0 = l0-1 (wrap)
    __shared__ float xmw[64][4];
    __shared__ float mn[21], rs[21];
    if (tid < 21) { mn[tid] = meanb[b * 21 + tid]; rs[tid] = rstdb[b * 21 + tid]; }
    float twr[63];
    {
        const float* tp = tokw + tid * 63;
        #pragma unroll
        for (int i = 0; i < 63; i++) twr[i] = tp[i];
    }
    float tbr[4];
    #pragma unroll
    for (int k = 0; k < 4; k++) tbr[k] = tembw[tid * 4 + k];
    __syncthreads();
    for (int i = tid; i < 1386; i += 256) {
        int row = i / 21, c = i - row * 21;
        int gl = (l0 - 1 + row + 1024) & 1023;
        xw[row][c] = (xe[(size_t)(b * 1024 + gl) * 21 + c] - mn[c]) * rs[c];
    }
    {
        int row = tid >> 2, c = tid & 3;
        xmw[row][c] = xm[(size_t)(b * 1024 + l0 + row) * 4 + c];
    }
    __syncthreads();
    int d = tid;
    float acc2 = 0.f, acc1 = 0.f;   // pending partial sums for out[r-2], out[r-1]
    for (int r = 0; r < 66; r++) {
        float s0 = 0.f, s1 = 0.f, s2 = 0.f;
        #pragma unroll
        for (int c = 0; c < 21; c++) {
            float xv = xw[r][c];
            s0 += xv * twr[c * 3 + 0];
            s1 += xv * twr[c * 3 + 1];
            s2 += xv * twr[c * 3 + 2];
        }
        if (r >= 2) {
            int li = r - 2;
            float acc = acc2 + s2 + pe[(size_t)(l0 + li) * 256 + d];
            #pragma unroll
            for (int k = 0; k < 4; k++) acc += xmw[li][k] * tbr[k];
            size_t o = (size_t)(b * 1024 + l0 + li) * 256 + d;
            h[o] = acc;
            hbf[o] = f2b(acc);
        }
        acc2 = acc1 + s1;
        acc1 = s0;
    }
}

// ---------------- in_proj GEMM: 64x64/wave, split store z|xBCdt ----------------
// A[32768x256] bf16, W[1216x256] bf16. tiles: 512 x 19.
__global__ __launch_bounds__(256) void gemm_ip(const ushort_t* __restrict__ A,
        const ushort_t* __restrict__ W, ushort_t* __restrict__ zbuf,
        ushort_t* __restrict__ xbuf) {
    int lane = threadIdx.x & 63;
    int wid = blockIdx.x * 4 + (threadIdx.x >> 6);
    int tm = wid / 19, tn = wid - tm * 19;
    int m0 = tm * 64, n0 = tn * 64;
    int rr = lane & 15, quad = lane >> 4;
    const ushort_t* ap = A + (size_t)(m0 + rr) * 256 + quad * 8;
    const ushort_t* wp = W + (size_t)(n0 + rr) * 256 + quad * 8;
    f32x4 acc[16];
    #pragma unroll
    for (int i = 0; i < 16; i++) acc[i] = (f32x4){0.f, 0.f, 0.f, 0.f};
    #pragma unroll
    for (int k = 0; k < 256; k += 32) {
        short8 a[4], bb[4];
        #pragma unroll
        for (int i = 0; i < 4; i++) a[i] = *(const short8*)(ap + (size_t)i * 16 * 256 + k);
        #pragma unroll
        for (int j = 0; j < 4; j++) bb[j] = *(const short8*)(wp + (size_t)j * 16 * 256 + k);
        #pragma unroll
        for (int i = 0; i < 4; i++)
            #pragma unroll
            for (int j = 0; j < 4; j++)
                acc[i * 4 + j] = __builtin_amdgcn_mfma_f32_16x16x32_bf16(a[i], bb[j], acc[i * 4 + j], 0, 0, 0);
    }
    #pragma unroll
    for (int i = 0; i < 4; i++) {
        int mrow = m0 + i * 16 + quad * 4;
        #pragma unroll
        for (int j = 0; j < 4; j++) {
            int n = n0 + j * 16 + rr;
            #pragma unroll
            for (int r2 = 0; r2 < 4; r2++) {
                ushort_t v = f2b(acc[i * 4 + j][r2]);
                if (tn < 8) zbuf[(size_t)(mrow + r2) * 512 + n] = v;
                else if (n < 1160) xbuf[(size_t)(mrow + r2) * 704 + (n - 512)] = v;
            }
        }
    }
}

// ---------------- causal depthwise conv + bias + silu ----------------
// 8 ch x 4 l per thread; weights hoisted via coalesced float4 loads (cwt[k][640]).
__global__ __launch_bounds__(256) void conv_kernel(const ushort_t* __restrict__ xbuf,
        const float* __restrict__ cwt, const float* __restrict__ cb,
        ushort_t* __restrict__ xc) {
    int idx = blockIdx.x * 256 + threadIdx.x;   // < 8192*80
    int g = idx % 80;
    int rt = idx / 80;
    int ch0 = g * 8;
    int b = rt >> 8;
    int l0 = (rt & 255) << 2;
    float wgt[4][8];
    #pragma unroll
    for (int k = 0; k < 4; k++) {
        float4 w0 = *(const float4*)(cwt + k * 640 + ch0);
        float4 w1 = *(const float4*)(cwt + k * 640 + ch0 + 4);
        wgt[k][0] = w0.x; wgt[k][1] = w0.y; wgt[k][2] = w0.z; wgt[k][3] = w0.w;
        wgt[k][4] = w1.x; wgt[k][5] = w1.y; wgt[k][6] = w1.z; wgt[k][7] = w1.w;
    }
    float bias[8];
    {
        float4 b0 = *(const float4*)(cb + ch0);
        float4 b1 = *(const float4*)(cb + ch0 + 4);
        bias[0] = b0.x; bias[1] = b0.y; bias[2] = b0.z; bias[3] = b0.w;
        bias[4] = b1.x; bias[5] = b1.y; bias[6] = b1.z; bias[7] = b1.w;
    }
    short8 xr[7];
    const ushort_t* base = xbuf + (size_t)(b * 1024 + l0) * 704 + ch0;
    #pragma unroll
    for (int i = 0; i < 7; i++) {
        int ll = l0 - 3 + i;
        if (ll >= 0) xr[i] = *(const short8*)(base + (ptrdiff_t)(i - 3) * 704);
        else         xr[i] = (short8){0, 0, 0, 0, 0, 0, 0, 0};
    }
    #pragma unroll
    for (int lo = 0; lo < 4; lo++) {
        float acc[8];
        #pragma unroll
        for (int j = 0; j < 8; j++) acc[j] = bias[j];
        #pragma unroll
        for (int k = 0; k < 4; k++) {
            #pragma unroll
            for (int j = 0; j < 8; j++)
                acc[j] += b2f(((ushort_t*)&xr[lo + k])[j]) * wgt[k][j];
        }
        short8 o;
        #pragma unroll
        for (int j = 0; j < 8; j++) ((ushort_t*)&o)[j] = f2b(silu_f(acc[j]));
        *(short8*)(xc + (size_t)(b * 1024 + l0 + lo) * 640 + ch0) = o;
    }
}

// ---------------- dt = softplus(dt_raw + bias) ----------------
__global__ __launch_bounds__(256) void dt_kernel(const ushort_t* __restrict__ xbuf,
        const float* __restrict__ dtb, float* __restrict__ dts) {
    int idx = blockIdx.x * 256 + threadIdx.x;   // < 262144
    int r = idx >> 3, hh = idx & 7;
    float x = b2f(xbuf[(size_t)r * 704 + 640 + hh]) + dtb[hh];
    dts[idx] = (x > 20.f) ? x : log1pf(__expf(x));
}

// ---------------- SSD A: chunk states = (B*dec)^T @ X per (b,h,chunk) ----------------
__global__ __launch_bounds__(256) void ssd_stateA(const ushort_t* __restrict__ xc,
        const float* __restrict__ dts, const float* __restrict__ alog,
        float* __restrict__ stbuf, float* __restrict__ acbuf) {
    int idx = blockIdx.x;               // bh*16 + chunk
    int bh = idx >> 4, chunk = idx & 15;
    int b = bh >> 3, h = bh & 7;
    int l0 = chunk * 64;
    float Ah = -__expf(alog[h]);
    int tid = threadIdx.x;
    int q = tid >> 2, pb = (tid & 3) * 16;

    __shared__ ushort_t Bt[64][72], Xt[64][72];
    __shared__ float dec_s[64];

    const ushort_t* xrow = xc + (size_t)(b * 1024 + l0 + q) * 640;
    ushort_t bv[16], xv[16];
    *(short8*)&bv[0] = *(const short8*)(xrow + 512 + pb);
    *(short8*)&bv[8] = *(const short8*)(xrow + 512 + pb + 8);
    *(short8*)&xv[0] = *(const short8*)(xrow + h * 64 + pb);
    *(short8*)&xv[8] = *(const short8*)(xrow + h * 64 + pb + 8);
    #pragma unroll
    for (int j = 0; j < 16; j++) Xt[pb + j][q] = xv[j];

    if (tid < 64) {
        float d = dts[(size_t)(b * 1024 + l0 + tid) * 8 + h];
        float a = d * Ah;
        #pragma unroll
        for (int off = 1; off < 64; off <<= 1) {
            float t = __shfl_up(a, off, 64);
            if (tid >= off) a += t;
        }
        acbuf[(size_t)idx * 64 + tid] = a;
        float tot = __shfl(a, 63, 64);
        dec_s[tid] = __expf(tot - a) * d;
    }
    __syncthreads();
    {
        float dq = dec_s[q];
        #pragma unroll
        for (int j = 0; j < 16; j++) Bt[pb + j][q] = f2b(b2f(bv[j]) * dq);
    }
    __syncthreads();

    int w = tid >> 6, lane = tid & 63;
    int rr = lane & 15, quad = lane >> 4, qb = w * 16;
    f32x4 acc[4];
    #pragma unroll
    for (int t = 0; t < 4; t++) acc[t] = (f32x4){0.f, 0.f, 0.f, 0.f};
    #pragma unroll
    for (int ks = 0; ks < 2; ks++) {
        short8 a = *(const short8*)(&Bt[qb + rr][ks * 32 + quad * 8]);
        #pragma unroll
        for (int t = 0; t < 4; t++) {
            short8 bb = *(const short8*)(&Xt[t * 16 + rr][ks * 32 + quad * 8]);
            acc[t] = __builtin_amdgcn_mfma_f32_16x16x32_bf16(a, bb, acc[t], 0, 0, 0);
        }
    }
    float* sb = stbuf + (size_t)idx * 4096;
    #pragma unroll
    for (int t = 0; t < 4; t++) {
        int p = t * 16 + rr;
        #pragma unroll
        for (int r2 = 0; r2 < 4; r2++) {
            int nn = qb + quad * 4 + r2;
            sb[nn * 64 + p] = acc[t][r2];
        }
    }
}

// ---------------- SSD B: scan chunk states in place (4-way split) ----------------
__global__ __launch_bounds__(256) void ssd_scan(float* __restrict__ stbuf,
        const float* __restrict__ acbuf) {
    int bh = blockIdx.x >> 2, sl = blockIdx.x & 3;
    int tid = threadIdx.x;
    size_t boff = (size_t)sl * 1024 + tid * 4;
    float4 S = make_float4(0.f, 0.f, 0.f, 0.f);
    for (int c = 0; c < 16; c++) {
        float* p = stbuf + ((size_t)bh * 16 + c) * 4096 + boff;
        float ad = __expf(acbuf[((size_t)bh * 16 + c) * 64 + 63]);
        float4 v = *(float4*)p;
        *(float4*)p = S;
        S.x = ad * S.x + v.x; S.y = ad * S.y + v.y;
        S.z = ad * S.z + v.z; S.w = ad * S.w + v.w;
    }
}

// ---------------- SSD C: y = Y_diag + Y_off + D*x -> bf16 ----------------
__global__ __launch_bounds__(256) void ssd_outBC(const ushort_t* __restrict__ xc,
        const float* __restrict__ dts, const float* __restrict__ alog,
        const float* __restrict__ dsk, const float* __restrict__ stbuf,
        ushort_t* __restrict__ ybuf) {
    int idx = blockIdx.x;
    int bh = idx >> 4, chunk = idx & 15;
    int b = bh >> 3, h = bh & 7;
    int l0 = chunk * 64;
    float Ah = -__expf(alog[h]);
    float Dh = dsk[h];
    int tid = threadIdx.x;
    int q = tid >> 2, pb = (tid & 3) * 16;

    __shared__ ushort_t Cs[64][72], Bs[64][72], Xt[64][72], Gs[64][72], Shi[64][72], Slo[64][72];
    __shared__ float acum_s[64], dtq_s[64], ea_s[64];

    const ushort_t* xrow = xc + (size_t)(b * 1024 + l0 + q) * 640;
    *(short8*)&Bs[q][pb]     = *(const short8*)(xrow + 512 + pb);
    *(short8*)&Bs[q][pb + 8] = *(const short8*)(xrow + 512 + pb + 8);
    *(short8*)&Cs[q][pb]     = *(const short8*)(xrow + 576 + pb);
    *(short8*)&Cs[q][pb + 8] = *(const short8*)(xrow + 576 + pb + 8);
    ushort_t xv[16];
    *(short8*)&xv[0] = *(const short8*)(xrow + h * 64 + pb);
    *(short8*)&xv[8] = *(const short8*)(xrow + h * 64 + pb + 8);
    #pragma unroll
    for (int j = 0; j < 16; j++) Xt[pb + j][q] = xv[j];
    {
        const float* sp = stbuf + (size_t)idx * 4096 + q * 64 + pb;
        #pragma unroll
        for (int j = 0; j < 16; j++) {
            float s = sp[j];
            ushort_t hi = f2b(s);
            Shi[pb + j][q] = hi;
            Slo[pb + j][q] = f2b(s - b2f(hi));
        }
    }
    if (tid < 64) {
        float d = dts[(size_t)(b * 1024 + l0 + tid) * 8 + h];
        dtq_s[tid] = d;
        float a = d * Ah;
        #pragma unroll
        for (int off = 1; off < 64; off <<= 1) {
            float t = __shfl_up(a, off, 64);
            if (tid >= off) a += t;
        }
        acum_s[tid] = a;
        ea_s[tid] = __expf(a);
    }
    __syncthreads();

    int w = tid >> 6, lane = tid & 63;
    int rr = lane & 15, quad = lane >> 4, qb = w * 16;

    // mm1: G = C.B^T masked -> Gs bf16
    {
        f32x4 g[4];
        #pragma unroll
        for (int t = 0; t < 4; t++) g[t] = (f32x4){0.f, 0.f, 0.f, 0.f};
        #pragma unroll
        for (int ks = 0; ks < 2; ks++) {
            short8 a = *(const short8*)(&Cs[qb + rr][ks * 32 + quad * 8]);
            #pragma unroll
            for (int t = 0; t < 4; t++) {
                short8 bb = *(const short8*)(&Bs[t * 16 + rr][ks * 32 + quad * 8]);
                g[t] = __builtin_amdgcn_mfma_f32_16x16x32_bf16(a, bb, g[t], 0, 0, 0);
            }
        }
        #pragma unroll
        for (int t = 0; t < 4; t++) {
            int s = t * 16 + rr;
            float as = acum_s[s], dss = dtq_s[s];
            #pragma unroll
            for (int r2 = 0; r2 < 4; r2++) {
                int qq = qb + quad * 4 + r2;
                float v = (s <= qq) ? g[t][r2] * __expf(acum_s[qq] - as) * dss : 0.f;
                Gs[qq][s] = f2b(v);
            }
        }
    }
    __syncthreads();

    // mm2: Y_diag = G@X ; Y_off = C@(Shi+Slo)
    f32x4 aD[4], aO[4];
    #pragma unroll
    for (int t = 0; t < 4; t++) { aD[t] = (f32x4){0.f,0.f,0.f,0.f}; aO[t] = (f32x4){0.f,0.f,0.f,0.f}; }
    #pragma unroll
    for (int ks = 0; ks < 2; ks++) {
        short8 ga = *(const short8*)(&Gs[qb + rr][ks * 32 + quad * 8]);
        short8 ca = *(const short8*)(&Cs[qb + rr][ks * 32 + quad * 8]);
        #pragma unroll
        for (int t = 0; t < 4; t++) {
            short8 xb = *(const short8*)(&Xt[t * 16 + rr][ks * 32 + quad * 8]);
            short8 sh = *(const short8*)(&Shi[t * 16 + rr][ks * 32 + quad * 8]);
            short8 sl = *(const short8*)(&Slo[t * 16 + rr][ks * 32 + quad * 8]);
            aD[t] = __builtin_amdgcn_mfma_f32_16x16x32_bf16(ga, xb, aD[t], 0, 0, 0);
            aO[t] = __builtin_amdgcn_mfma_f32_16x16x32_bf16(ca, sh, aO[t], 0, 0, 0);
            aO[t] = __builtin_amdgcn_mfma_f32_16x16x32_bf16(ca, sl, aO[t], 0, 0, 0);
        }
    }
    #pragma unroll
    for (int t = 0; t < 4; t++) {
        int p = t * 16 + rr;
        #pragma unroll
        for (int r2 = 0; r2 < 4; r2++) {
            int qq = qb + quad * 4 + r2;
            float y = aD[t][r2] + ea_s[qq] * aO[t][r2] + Dh * b2f(Xt[p][qq]);
            ybuf[(size_t)(b * 1024 + l0 + qq) * 512 + h * 64 + p] = f2b(y);
        }
    }
}

// ---------------- gate: y = y*silu(z), RMSnorm*gw (in-place bf16) ----------------
__global__ __launch_bounds__(256) void gate_kernel(const ushort_t* __restrict__ zbuf,
        ushort_t* __restrict__ ybuf, const float* __restrict__ gw) {
    int r = blockIdx.x, tid = threadIdx.x;
    size_t base = (size_t)r * 512;
    float z0 = b2f(zbuf[base + tid]);
    float z1 = b2f(zbuf[base + tid + 256]);
    float v0 = b2f(ybuf[base + tid]) * silu_f(z0);
    float v1 = b2f(ybuf[base + tid + 256]) * silu_f(z1);
    float ss = v0 * v0 + v1 * v1;
    __shared__ float red[4];
    for (int o = 32; o > 0; o >>= 1) ss += __shfl_down(ss, o, 64);
    if ((tid & 63) == 0) red[tid >> 6] = ss;
    __syncthreads();
    float tot = red[0] + red[1] + red[2] + red[3];
    float rms = rsqrtf(tot * (1.f / 512.f) + 1e-5f);
    ybuf[base + tid] = f2b(v0 * rms * gw[tid]);
    ybuf[base + tid + 256] = f2b(v1 * rms * gw[tid + 256]);
}

// ---------------- out_proj GEMM: 64x64/wave, fp32 out ----------------
__global__ __launch_bounds__(256) void gemm_op(const ushort_t* __restrict__ A,
        const ushort_t* __restrict__ W, float* __restrict__ C) {
    int lane = threadIdx.x & 63;
    int wid = blockIdx.x * 4 + (threadIdx.x >> 6);
    int tm = wid >> 2, tn = wid & 3;            // tiles: 512 m x 4 n
    int m0 = tm * 64, n0 = tn * 64;
    int rr = lane & 15, quad = lane >> 4;
    const ushort_t* ap = A + (size_t)(m0 + rr) * 512 + quad * 8;
    const ushort_t* wp = W + (size_t)(n0 + rr) * 512 + quad * 8;
    f32x4 acc[16];
    #pragma unroll
    for (int i = 0; i < 16; i++) acc[i] = (f32x4){0.f, 0.f, 0.f, 0.f};
    #pragma unroll
    for (int k = 0; k < 512; k += 32) {
        short8 a[4], bb[4];
        #pragma unroll
        for (int i = 0; i < 4; i++) a[i] = *(const short8*)(ap + (size_t)i * 16 * 512 + k);
        #pragma unroll
        for (int j = 0; j < 4; j++) bb[j] = *(const short8*)(wp + (size_t)j * 16 * 512 + k);
        #pragma unroll
        for (int i = 0; i < 4; i++)
            #pragma unroll
            for (int j = 0; j < 4; j++)
                acc[i * 4 + j] = __builtin_amdgcn_mfma_f32_16x16x32_bf16(a[i], bb[j], acc[i * 4 + j], 0, 0, 0);
    }
    #pragma unroll
    for (int i = 0; i < 4; i++) {
        int mrow = m0 + i * 16 + quad * 4;
        #pragma unroll
        for (int j = 0; j < 4; j++) {
            int n = n0 + j * 16 + rr;
            #pragma unroll
            for (int r2 = 0; r2 < 4; r2++)
                C[(size_t)(mrow + r2) * 256 + n] = acc[i * 4 + j][r2];
        }
    }
}

// ---------------- residual + layernorm ----------------
__global__ __launch_bounds__(256) void resln_kernel(float* __restrict__ h,
        ushort_t* __restrict__ hbf, const float* __restrict__ yp,
        const float* __restrict__ g, const float* __restrict__ bb) {
    int r = blockIdx.x, tid = threadIdx.x;
    size_t base = (size_t)r * 256;
    float x = h[base + tid] + yp[base + tid];
    float s = x, s2 = x * x;
    __shared__ float r1[4], r2[4];
    for (int o = 32; o > 0; o >>= 1) { s += __shfl_down(s, o, 64); s2 += __shfl_down(s2, o, 64); }
    if ((tid & 63) == 0) { r1[tid >> 6] = s; r2[tid >> 6] = s2; }
    __syncthreads();
    float S = r1[0] + r1[1] + r1[2] + r1[3];
    float S2 = r2[0] + r2[1] + r2[2] + r2[3];
    float mu = S * (1.f / 256.f);
    float var = S2 * (1.f / 256.f) - mu * mu;
    float o = (x - mu) * rsqrtf(var + 1e-5f) * g[tid] + bb[tid];
    h[base + tid] = o;
    hbf[base + tid] = f2b(o);
}

// ---------------- head ----------------
__global__ __launch_bounds__(256) void head_kernel(const float* __restrict__ h,
        const float* __restrict__ hw, const float* __restrict__ stdb,
        const float* __restrict__ meanb, float* __restrict__ out) {
    int blk = blockIdx.x;       // b*192 + t
    int b = blk / 192, t = blk - b * 192;
    int l = 832 + t;
    int tid = threadIdx.x;
    __shared__ float hr[256];
    hr[tid] = h[(size_t)(b * 1024 + l) * 256 + tid];
    __syncthreads();
    if (tid < 21) {
        float acc = 0.f;
        for (int k = 0; k < 256; k++) acc += hr[k] * hw[tid * 256 + k];
        out[(size_t)blk * 21 + tid] = acc * stdb[b * 21 + tid] + meanb[b * 21 + tid];
    }
}

extern "C" void kernel_launch(void* const* d_in, const int* in_sizes, int n_in,
                              void* d_out, int out_size, void* d_ws, size_t ws_size,
                              hipStream_t stream) {
    const float* x_enc  = (const float*)d_in[0];
    const float* x_mark = (const float*)d_in[1];
    const float* tokw   = (const float*)d_in[4];
    const float* tembw  = (const float*)d_in[5];
    const float* ln_g   = (const float*)d_in[6];
    const float* ln_b   = (const float*)d_in[7];
    const float* ipw    = (const float*)d_in[8];
    const float* cw     = (const float*)d_in[9];
    const float* cb     = (const float*)d_in[10];
    const float* dtb    = (const float*)d_in[11];
    const float* alog   = (const float*)d_in[12];
    const float* dsk    = (const float*)d_in[13];
    const float* gw     = (const float*)d_in[14];
    const float* opw    = (const float*)d_in[15];
    const float* hw     = (const float*)d_in[16];
    float* out = (float*)d_out;

    char* w = (char*)d_ws;
    size_t off = 0;
    auto alloc = [&](size_t bytes) -> void* {
        void* p = w + off;
        off += (bytes + 255) & ~(size_t)255;
        return p;
    };
    float* meanb  = (float*)alloc(672 * 4);
    float* stdb   = (float*)alloc(672 * 4);
    float* rstdb  = (float*)alloc(672 * 4);
    float* dts    = (float*)alloc((size_t)262144 * 4);            // 1.05 MB
    float* pebuf  = (float*)alloc((size_t)262144 * 4);            // 1.05 MB
    float* cwt    = (float*)alloc((size_t)10240 * 4);             // 40 KB
    float* hbuf   = (float*)alloc((size_t)8388608 * 4);           // 33.55 MB
    ushort_t* hbf = (ushort_t*)alloc((size_t)8388608 * 2);        // 16.78 MB
    ushort_t* zbuf= (ushort_t*)alloc((size_t)32768 * 512 * 2);    // 33.55 MB
    ushort_t* xc  = (ushort_t*)alloc((size_t)32768 * 640 * 2);    // 41.94 MB
    char* R       = (char*)alloc((size_t)71303168);               // 71.30 MB union
    ushort_t* ybuf= (ushort_t*)alloc((size_t)32768 * 512 * 2);    // 33.55 MB
    ushort_t* wipb= (ushort_t*)alloc((size_t)4 * 1216 * 256 * 2); // 2.49 MB
    ushort_t* wopb= (ushort_t*)alloc((size_t)4 * 256 * 512 * 2);  // 1.05 MB
    // region R aliases: xbuf (gemm_ip out) dies after conv+dt; stbuf/acbuf take over
    ushort_t* xbuf = (ushort_t*)R;                        // 32768 x 704 bf16 = 46.14 MB
    float* stbuf   = (float*)R;                           // 256*16*4096 fp32 = 67.11 MB
    float* acbuf   = (float*)(R + 67108864);              // 256*16*64 fp32 = 4.19 MB
    float* yproj   = (float*)xc;                          // alias: xc dead once gemm_op runs
    (void)ws_size; (void)in_sizes; (void)n_in; (void)out_size;
    // total ~236.4 MB

    stats_kernel<<<672, 256, 0, stream>>>(x_enc, meanb, stdb, rstdb);
    pe_kernel<<<1024, 256, 0, stream>>>(pebuf);
    cvt_pad_ip<<<4864, 256, 0, stream>>>(ipw, wipb);
    cvt_kernel<<<2048, 256, 0, stream>>>(opw, wopb, 524288);
    cvt_convw<<<40, 256, 0, stream>>>(cw, cwt);
    embed3_kernel<<<512, 256, 0, stream>>>(x_enc, x_mark, tokw, tembw, pebuf,
                                           meanb, rstdb, hbuf, hbf);

    for (int layer = 0; layer < 4; layer++) {
        // in_proj: 512x19 tiles = 9728 waves -> 2432 blocks
        gemm_ip<<<2432, 256, 0, stream>>>(hbf, wipb + (size_t)layer * 1216 * 256, zbuf, xbuf);
        conv_kernel<<<2560, 256, 0, stream>>>(xbuf, cwt + layer * 2560, cb + layer * 640, xc);
        dt_kernel<<<1024, 256, 0, stream>>>(xbuf, dtb + layer * 8, dts);
        // xbuf now dead -> stbuf/acbuf overwrite region R
        ssd_stateA<<<4096, 256, 0, stream>>>(xc, dts, alog + layer * 8, stbuf, acbuf);
        ssd_scan<<<1024, 256, 0, stream>>>(stbuf, acbuf);
        ssd_outBC<<<4096, 256, 0, stream>>>(xc, dts, alog + layer * 8, dsk + layer * 8,
                                            stbuf, ybuf);
        gate_kernel<<<32768, 256, 0, stream>>>(zbuf, ybuf, gw + layer * 512);
        // out_proj: 512x4 tiles = 2048 waves -> 512 blocks
        gemm_op<<<512, 256, 0, stream>>>(ybuf, wopb + (size_t)layer * 256 * 512, yproj);
        resln_kernel<<<32768, 256, 0, stream>>>(hbuf, hbf, yproj,
                                                ln_g + layer * 256, ln_b + layer * 256);
    }

    head_kernel<<<6144, 256, 0, stream>>>(hbuf, hw, stdb, meanb, out);
}

// Round 7
// 1013.306 us; speedup vs baseline: 3.7253x; 1.1809x over previous
//
#include <hip/hip_runtime.h>
#include <hip/hip_bf16.h>

// Model: 4-layer Mamba2 TS model. B=32 L=1024 DM=256 DI=512 DST=64 NH=8 HD=64
// DC=4 Q=64 chunks=16 DIP=1160(pad 1280) CONVD=640 PRED=192 CO=21.
// I/O fp32. bf16 MFMA operands, fp32 accum. WS ~236.5 MB (<~256 limit).
// R6->R7: both GEMMs moved to m97-ladder structure: 128x128 block tile,
// 4 waves 2x2, BK=32, global_load_lds(16B) staging, ds_read_b128 frags.
// R6 gemm_ip was 87.5us @ MfmaUtil 9% (load-latency-bound, 8 private global
// loads/K-step/wave, no sharing). Frag k-order identical -> same numerics.

typedef unsigned short ushort_t;
typedef unsigned int uint_t;
typedef __attribute__((ext_vector_type(8))) short short8;
typedef __attribute__((ext_vector_type(4))) float f32x4;

__device__ __forceinline__ float b2f(ushort_t u) {
    uint_t v = ((uint_t)u) << 16;
    return __builtin_bit_cast(float, v);
}
__device__ __forceinline__ ushort_t f2b(float f) {
    uint_t u = __builtin_bit_cast(uint_t, f);
    uint_t r = (u + 0x7FFFu + ((u >> 16) & 1u)) >> 16;
    return (ushort_t)r;
}
__device__ __forceinline__ float silu_f(float x) {
    return x / (1.f + __expf(-x));
}
__device__ __forceinline__ void gl_lds16(const ushort_t* g, ushort_t* l) {
    __builtin_amdgcn_global_load_lds(
        (const __attribute__((address_space(1))) unsigned int*)g,
        (__attribute__((address_space(3))) unsigned int*)l, 16, 0, 0);
}

// ---------------- weight converts ----------------
__global__ __launch_bounds__(256) void cvt_kernel(const float* __restrict__ in,
        ushort_t* __restrict__ out, int n) {
    int i = blockIdx.x * 256 + threadIdx.x;
    if (i < n) out[i] = f2b(in[i]);
}
// in_proj w: [4][1160][256] -> bf16 [4][1280][256], rows >=1160 zero
__global__ __launch_bounds__(256) void cvt_pad_ip(const float* __restrict__ in,
        ushort_t* __restrict__ out) {
    int i = blockIdx.x * 256 + threadIdx.x;     // < 4*1280*256
    if (i >= 4 * 1280 * 256) return;
    int layer = i / (1280 * 256);
    int rem = i - layer * 1280 * 256;
    int n = rem >> 8, k = rem & 255;
    out[i] = (n < 1160) ? f2b(in[(size_t)layer * 1160 * 256 + n * 256 + k]) : (ushort_t)0;
}
// conv w: [4][640][4] -> [4][4][640] fp32 transpose
__global__ __launch_bounds__(256) void cvt_convw(const float* __restrict__ in,
        float* __restrict__ out) {
    int i = blockIdx.x * 256 + threadIdx.x;     // < 4*2560
    if (i >= 10240) return;
    int layer = i / 2560;
    int rem = i - layer * 2560;
    int k = rem / 640, ch = rem - k * 640;
    out[i] = in[layer * 2560 + ch * 4 + k];
}

// ---------------- pos-emb table: pe[l][d], computed once ----------------
__global__ __launch_bounds__(256) void pe_kernel(float* __restrict__ pe) {
    int l = blockIdx.x, d = threadIdx.x;
    float div = __expf((float)(d & ~1) * (-9.210340371976184f / 256.0f));
    float arg = (float)l * div;
    pe[l * 256 + d] = (d & 1) ? cosf(arg) : sinf(arg);
}

// ---------------- stats ----------------
__global__ __launch_bounds__(256) void stats_kernel(const float* __restrict__ xe,
        float* __restrict__ meanb, float* __restrict__ stdb, float* __restrict__ rstdb) {
    int bi = blockIdx.x;
    int b = bi / 21, c = bi - b * 21;
    int tid = threadIdx.x;
    float s = 0.f, s2 = 0.f;
    for (int l = tid; l < 1024; l += 256) {
        float v = xe[(b * 1024 + l) * 21 + c];
        s += v; s2 += v * v;
    }
    __shared__ float r1[4], r2[4];
    for (int o = 32; o > 0; o >>= 1) { s += __shfl_down(s, o, 64); s2 += __shfl_down(s2, o, 64); }
    if ((tid & 63) == 0) { r1[tid >> 6] = s; r2[tid >> 6] = s2; }
    __syncthreads();
    if (tid == 0) {
        float S = r1[0] + r1[1] + r1[2] + r1[3];
        float S2 = r2[0] + r2[1] + r2[2] + r2[3];
        float m = S * (1.f / 1024.f);
        float var = S2 * (1.f / 1024.f) - m * m;
        float sd = sqrtf(var + 1e-5f);
        meanb[bi] = m; stdb[bi] = sd; rstdb[bi] = 1.f / sd;
    }
}

// ---------------- embedding: sliding-window, tokw in registers ----------------
__global__ __launch_bounds__(256) void embed3_kernel(const float* __restrict__ xe,
        const float* __restrict__ xm, const float* __restrict__ tokw,
        const float* __restrict__ tembw, const float* __restrict__ pe,
        const float* __restrict__ meanb, const float* __restrict__ rstdb,
        float* __restrict__ h, ushort_t* __restrict__ hbf) {
    int blk = blockIdx.x;               // b*16 + tile
    int b = blk >> 4, t = blk & 15;
    int l0 = t * 64;
    int tid = threadIdx.x;              // = d
    __shared__ float xw[66][22];        // normalized x window, row0 = l0-1 (wrap)
    __shared__ float xmw[64][4];
    __shared__ float mn[21], rs[21];
    if (tid < 21) { mn[tid] = meanb[b * 21 + tid]; rs[tid] = rstdb[b * 21 + tid]; }
    float twr[63];
    {
        const float* tp = tokw + tid * 63;
        #pragma unroll
        for (int i = 0; i < 63; i++) twr[i] = tp[i];
    }
    float tbr[4];
    #pragma unroll
    for (int k = 0; k < 4; k++) tbr[k] = tembw[tid * 4 + k];
    __syncthreads();
    for (int i = tid; i < 1386; i += 256) {
        int row = i / 21, c = i - row * 21;
        int gl = (l0 - 1 + row + 1024) & 1023;
        xw[row][c] = (xe[(size_t)(b * 1024 + gl) * 21 + c] - mn[c]) * rs[c];
    }
    {
        int row = tid >> 2, c = tid & 3;
        xmw[row][c] = xm[(size_t)(b * 1024 + l0 + row) * 4 + c];
    }
    __syncthreads();
    int d = tid;
    float acc2 = 0.f, acc1 = 0.f;   // pending partial sums for out[r-2], out[r-1]
    for (int r = 0; r < 66; r++) {
        float s0 = 0.f, s1 = 0.f, s2 = 0.f;
        #pragma unroll
        for (int c = 0; c < 21; c++) {
            float xv = xw[r][c];
            s0 += xv * twr[c * 3 + 0];
            s1 += xv * twr[c * 3 + 1];
            s2 += xv * twr[c * 3 + 2];
        }
        if (r >= 2) {
            int li = r - 2;
            float acc = acc2 + s2 + pe[(size_t)(l0 + li) * 256 + d];
            #pragma unroll
            for (int k = 0; k < 4; k++) acc += xmw[li][k] * tbr[k];
            size_t o = (size_t)(b * 1024 + l0 + li) * 256 + d;
            h[o] = acc;
            hbf[o] = f2b(acc);
        }
        acc2 = acc1 + s1;
        acc1 = s0;
    }
}

// ---------------- 128x128 LDS-staged GEMM mainloop (m97 structure) ----------------
// A rows stride == KDIM, W rows stride == KDIM. 4 waves in 2x2. BK=32.
template<int KDIM>
__device__ __forceinline__ void gemm128_main(const ushort_t* __restrict__ Ab,
        const ushort_t* __restrict__ Wb, ushort_t* sA, ushort_t* sW,
        f32x4 (&acc)[16], int m0, int n0) {
    int tid = threadIdx.x;
    int w = tid >> 6, lane = tid & 63;
    int wm = w >> 1, wn = w & 1;
    int rr = lane & 15, quad = lane >> 4;
    int srow0 = w * 32 + (lane >> 2);       // staging row (+ j*16)
    int skk = (lane & 3) * 8;               // staging k-offset (shorts)
    int sl0 = w * 1024 + lane * 8;          // staging LDS index (+ j*512)
    for (int k0 = 0; k0 < KDIM; k0 += 32) {
        __syncthreads();                    // prev MFMA reads done before overwrite
        #pragma unroll
        for (int j = 0; j < 2; j++) {
            int row = srow0 + j * 16;
            gl_lds16(Ab + (size_t)(m0 + row) * KDIM + k0 + skk, &sA[sl0 + j * 512]);
            gl_lds16(Wb + (size_t)(n0 + row) * KDIM + k0 + skk, &sW[sl0 + j * 512]);
        }
        __syncthreads();                    // compiler drains vmcnt before barrier
        short8 a[4], b[4];
        #pragma unroll
        for (int i = 0; i < 4; i++)
            a[i] = *(const short8*)&sA[(wm * 64 + i * 16 + rr) * 32 + quad * 8];
        #pragma unroll
        for (int j = 0; j < 4; j++)
            b[j] = *(const short8*)&sW[(wn * 64 + j * 16 + rr) * 32 + quad * 8];
        #pragma unroll
        for (int i = 0; i < 4; i++)
            #pragma unroll
            for (int j = 0; j < 4; j++)
                acc[i * 4 + j] = __builtin_amdgcn_mfma_f32_16x16x32_bf16(a[i], b[j], acc[i * 4 + j], 0, 0, 0);
    }
}

// in_proj: A[32768x256] x W[1280x256] -> split z (n<512) | xBC/dt (512<=n<1160)
__global__ __launch_bounds__(256) void gemm_ip(const ushort_t* __restrict__ A,
        const ushort_t* __restrict__ W, ushort_t* __restrict__ zbuf,
        ushort_t* __restrict__ xbuf) {
    int blk = blockIdx.x;               // 2560 = 256 m-tiles x 10 n-tiles
    int tm = blk / 10, tn = blk - tm * 10;
    int m0 = tm * 128, n0 = tn * 128;
    __shared__ ushort_t sA[4096], sW[4096];
    f32x4 acc[16];
    #pragma unroll
    for (int i = 0; i < 16; i++) acc[i] = (f32x4){0.f, 0.f, 0.f, 0.f};
    gemm128_main<256>(A, W, sA, sW, acc, m0, n0);
    int lane = threadIdx.x & 63, w = threadIdx.x >> 6;
    int wm = w >> 1, wn = w & 1;
    int rr = lane & 15, quad = lane >> 4;
    #pragma unroll
    for (int i = 0; i < 4; i++) {
        int mrow = m0 + wm * 64 + i * 16 + quad * 4;
        #pragma unroll
        for (int j = 0; j < 4; j++) {
            int n = n0 + wn * 64 + j * 16 + rr;
            #pragma unroll
            for (int r2 = 0; r2 < 4; r2++) {
                ushort_t v = f2b(acc[i * 4 + j][r2]);
                if (n < 512) zbuf[(size_t)(mrow + r2) * 512 + n] = v;
                else if (n < 1160) xbuf[(size_t)(mrow + r2) * 704 + (n - 512)] = v;
            }
        }
    }
}

// out_proj: A[32768x512] x W[256x512] -> C[32768x256] fp32
__global__ __launch_bounds__(256) void gemm_op(const ushort_t* __restrict__ A,
        const ushort_t* __restrict__ W, float* __restrict__ C) {
    int blk = blockIdx.x;               // 512 = 256 m-tiles x 2 n-tiles
    int tm = blk >> 1, tn = blk & 1;
    int m0 = tm * 128, n0 = tn * 128;
    __shared__ ushort_t sA[4096], sW[4096];
    f32x4 acc[16];
    #pragma unroll
    for (int i = 0; i < 16; i++) acc[i] = (f32x4){0.f, 0.f, 0.f, 0.f};
    gemm128_main<512>(A, W, sA, sW, acc, m0, n0);
    int lane = threadIdx.x & 63, w = threadIdx.x >> 6;
    int wm = w >> 1, wn = w & 1;
    int rr = lane & 15, quad = lane >> 4;
    #pragma unroll
    for (int i = 0; i < 4; i++) {
        int mrow = m0 + wm * 64 + i * 16 + quad * 4;
        #pragma unroll
        for (int j = 0; j < 4; j++) {
            int n = n0 + wn * 64 + j * 16 + rr;
            #pragma unroll
            for (int r2 = 0; r2 < 4; r2++)
                C[(size_t)(mrow + r2) * 256 + n] = acc[i * 4 + j][r2];
        }
    }
}

// ---------------- causal depthwise conv + bias + silu ----------------
// 8 ch x 4 l per thread; weights hoisted via coalesced float4 loads (cwt[k][640]).
__global__ __launch_bounds__(256) void conv_kernel(const ushort_t* __restrict__ xbuf,
        const float* __restrict__ cwt, const float* __restrict__ cb,
        ushort_t* __restrict__ xc) {
    int idx = blockIdx.x * 256 + threadIdx.x;   // < 8192*80
    int g = idx % 80;
    int rt = idx / 80;
    int ch0 = g * 8;
    int b = rt >> 8;
    int l0 = (rt & 255) << 2;
    float wgt[4][8];
    #pragma unroll
    for (int k = 0; k < 4; k++) {
        float4 w0 = *(const float4*)(cwt + k * 640 + ch0);
        float4 w1 = *(const float4*)(cwt + k * 640 + ch0 + 4);
        wgt[k][0] = w0.x; wgt[k][1] = w0.y; wgt[k][2] = w0.z; wgt[k][3] = w0.w;
        wgt[k][4] = w1.x; wgt[k][5] = w1.y; wgt[k][6] = w1.z; wgt[k][7] = w1.w;
    }
    float bias[8];
    {
        float4 b0 = *(const float4*)(cb + ch0);
        float4 b1 = *(const float4*)(cb + ch0 + 4);
        bias[0] = b0.x; bias[1] = b0.y; bias[2] = b0.z; bias[3] = b0.w;
        bias[4] = b1.x; bias[5] = b1.y; bias[6] = b1.z; bias[7] = b1.w;
    }
    short8 xr[7];
    const ushort_t* base = xbuf + (size_t)(b * 1024 + l0) * 704 + ch0;
    #pragma unroll
    for (int i = 0; i < 7; i++) {
        int ll = l0 - 3 + i;
        if (ll >= 0) xr[i] = *(const short8*)(base + (ptrdiff_t)(i - 3) * 704);
        else         xr[i] = (short8){0, 0, 0, 0, 0, 0, 0, 0};
    }
    #pragma unroll
    for (int lo = 0; lo < 4; lo++) {
        float acc[8];
        #pragma unroll
        for (int j = 0; j < 8; j++) acc[j] = bias[j];
        #pragma unroll
        for (int k = 0; k < 4; k++) {
            #pragma unroll
            for (int j = 0; j < 8; j++)
                acc[j] += b2f(((ushort_t*)&xr[lo + k])[j]) * wgt[k][j];
        }
        short8 o;
        #pragma unroll
        for (int j = 0; j < 8; j++) ((ushort_t*)&o)[j] = f2b(silu_f(acc[j]));
        *(short8*)(xc + (size_t)(b * 1024 + l0 + lo) * 640 + ch0) = o;
    }
}

// ---------------- dt = softplus(dt_raw + bias) ----------------
__global__ __launch_bounds__(256) void dt_kernel(const ushort_t* __restrict__ xbuf,
        const float* __restrict__ dtb, float* __restrict__ dts) {
    int idx = blockIdx.x * 256 + threadIdx.x;   // < 262144
    int r = idx >> 3, hh = idx & 7;
    float x = b2f(xbuf[(size_t)r * 704 + 640 + hh]) + dtb[hh];
    dts[idx] = (x > 20.f) ? x : log1pf(__expf(x));
}

// ---------------- SSD A: chunk states = (B*dec)^T @ X per (b,h,chunk) ----------------
__global__ __launch_bounds__(256) void ssd_stateA(const ushort_t* __restrict__ xc,
        const float* __restrict__ dts, const float* __restrict__ alog,
        float* __restrict__ stbuf, float* __restrict__ acbuf) {
    int idx = blockIdx.x;               // bh*16 + chunk
    int bh = idx >> 4, chunk = idx & 15;
    int b = bh >> 3, h = bh & 7;
    int l0 = chunk * 64;
    float Ah = -__expf(alog[h]);
    int tid = threadIdx.x;
    int q = tid >> 2, pb = (tid & 3) * 16;

    __shared__ ushort_t Bt[64][72], Xt[64][72];
    __shared__ float dec_s[64];

    const ushort_t* xrow = xc + (size_t)(b * 1024 + l0 + q) * 640;
    ushort_t bv[16], xv[16];
    *(short8*)&bv[0] = *(const short8*)(xrow + 512 + pb);
    *(short8*)&bv[8] = *(const short8*)(xrow + 512 + pb + 8);
    *(short8*)&xv[0] = *(const short8*)(xrow + h * 64 + pb);
    *(short8*)&xv[8] = *(const short8*)(xrow + h * 64 + pb + 8);
    #pragma unroll
    for (int j = 0; j < 16; j++) Xt[pb + j][q] = xv[j];

    if (tid < 64) {
        float d = dts[(size_t)(b * 1024 + l0 + tid) * 8 + h];
        float a = d * Ah;
        #pragma unroll
        for (int off = 1; off < 64; off <<= 1) {
            float t = __shfl_up(a, off, 64);
            if (tid >= off) a += t;
        }
        acbuf[(size_t)idx * 64 + tid] = a;
        float tot = __shfl(a, 63, 64);
        dec_s[tid] = __expf(tot - a) * d;
    }
    __syncthreads();
    {
        float dq = dec_s[q];
        #pragma unroll
        for (int j = 0; j < 16; j++) Bt[pb + j][q] = f2b(b2f(bv[j]) * dq);
    }
    __syncthreads();

    int w = tid >> 6, lane = tid & 63;
    int rr = lane & 15, quad = lane >> 4, qb = w * 16;
    f32x4 acc[4];
    #pragma unroll
    for (int t = 0; t < 4; t++) acc[t] = (f32x4){0.f, 0.f, 0.f, 0.f};
    #pragma unroll
    for (int ks = 0; ks < 2; ks++) {
        short8 a = *(const short8*)(&Bt[qb + rr][ks * 32 + quad * 8]);
        #pragma unroll
        for (int t = 0; t < 4; t++) {
            short8 bb = *(const short8*)(&Xt[t * 16 + rr][ks * 32 + quad * 8]);
            acc[t] = __builtin_amdgcn_mfma_f32_16x16x32_bf16(a, bb, acc[t], 0, 0, 0);
        }
    }
    float* sb = stbuf + (size_t)idx * 4096;
    #pragma unroll
    for (int t = 0; t < 4; t++) {
        int p = t * 16 + rr;
        #pragma unroll
        for (int r2 = 0; r2 < 4; r2++) {
            int nn = qb + quad * 4 + r2;
            sb[nn * 64 + p] = acc[t][r2];
        }
    }
}

// ---------------- SSD B: scan chunk states in place (4-way split) ----------------
__global__ __launch_bounds__(256) void ssd_scan(float* __restrict__ stbuf,
        const float* __restrict__ acbuf) {
    int bh = blockIdx.x >> 2, sl = blockIdx.x & 3;
    int tid = threadIdx.x;
    size_t boff = (size_t)sl * 1024 + tid * 4;
    float4 S = make_float4(0.f, 0.f, 0.f, 0.f);
    for (int c = 0; c < 16; c++) {
        float* p = stbuf + ((size_t)bh * 16 + c) * 4096 + boff;
        float ad = __expf(acbuf[((size_t)bh * 16 + c) * 64 + 63]);
        float4 v = *(float4*)p;
        *(float4*)p = S;
        S.x = ad * S.x + v.x; S.y = ad * S.y + v.y;
        S.z = ad * S.z + v.z; S.w = ad * S.w + v.w;
    }
}

// ---------------- SSD C: y = Y_diag + Y_off + D*x -> bf16 ----------------
__global__ __launch_bounds__(256) void ssd_outBC(const ushort_t* __restrict__ xc,
        const float* __restrict__ dts, const float* __restrict__ alog,
        const float* __restrict__ dsk, const float* __restrict__ stbuf,
        ushort_t* __restrict__ ybuf) {
    int idx = blockIdx.x;
    int bh = idx >> 4, chunk = idx & 15;
    int b = bh >> 3, h = bh & 7;
    int l0 = chunk * 64;
    float Ah = -__expf(alog[h]);
    float Dh = dsk[h];
    int tid = threadIdx.x;
    int q = tid >> 2, pb = (tid & 3) * 16;

    __shared__ ushort_t Cs[64][72], Bs[64][72], Xt[64][72], Gs[64][72], Shi[64][72], Slo[64][72];
    __shared__ float acum_s[64], dtq_s[64], ea_s[64];

    const ushort_t* xrow = xc + (size_t)(b * 1024 + l0 + q) * 640;
    *(short8*)&Bs[q][pb]     = *(const short8*)(xrow + 512 + pb);
    *(short8*)&Bs[q][pb + 8] = *(const short8*)(xrow + 512 + pb + 8);
    *(short8*)&Cs[q][pb]     = *(const short8*)(xrow + 576 + pb);
    *(short8*)&Cs[q][pb + 8] = *(const short8*)(xrow + 576 + pb + 8);
    ushort_t xv[16];
    *(short8*)&xv[0] = *(const short8*)(xrow + h * 64 + pb);
    *(short8*)&xv[8] = *(const short8*)(xrow + h * 64 + pb + 8);
    #pragma unroll
    for (int j = 0; j < 16; j++) Xt[pb + j][q] = xv[j];
    {
        const float* sp = stbuf + (size_t)idx * 4096 + q * 64 + pb;
        #pragma unroll
        for (int j = 0; j < 16; j++) {
            float s = sp[j];
            ushort_t hi = f2b(s);
            Shi[pb + j][q] = hi;
            Slo[pb + j][q] = f2b(s - b2f(hi));
        }
    }
    if (tid < 64) {
        float d = dts[(size_t)(b * 1024 + l0 + tid) * 8 + h];
        dtq_s[tid] = d;
        float a = d * Ah;
        #pragma unroll
        for (int off = 1; off < 64; off <<= 1) {
            float t = __shfl_up(a, off, 64);
            if (tid >= off) a += t;
        }
        acum_s[tid] = a;
        ea_s[tid] = __expf(a);
    }
    __syncthreads();

    int w = tid >> 6, lane = tid & 63;
    int rr = lane & 15, quad = lane >> 4, qb = w * 16;

    // mm1: G = C.B^T masked -> Gs bf16
    {
        f32x4 g[4];
        #pragma unroll
        for (int t = 0; t < 4; t++) g[t] = (f32x4){0.f, 0.f, 0.f, 0.f};
        #pragma unroll
        for (int ks = 0; ks < 2; ks++) {
            short8 a = *(const short8*)(&Cs[qb + rr][ks * 32 + quad * 8]);
            #pragma unroll
            for (int t = 0; t < 4; t++) {
                short8 bb = *(const short8*)(&Bs[t * 16 + rr][ks * 32 + quad * 8]);
                g[t] = __builtin_amdgcn_mfma_f32_16x16x32_bf16(a, bb, g[t], 0, 0, 0);
            }
        }
        #pragma unroll
        for (int t = 0; t < 4; t++) {
            int s = t * 16 + rr;
            float as = acum_s[s], dss = dtq_s[s];
            #pragma unroll
            for (int r2 = 0; r2 < 4; r2++) {
                int qq = qb + quad * 4 + r2;
                float v = (s <= qq) ? g[t][r2] * __expf(acum_s[qq] - as) * dss : 0.f;
                Gs[qq][s] = f2b(v);
            }
        }
    }
    __syncthreads();

    // mm2: Y_diag = G@X ; Y_off = C@(Shi+Slo)
    f32x4 aD[4], aO[4];
    #pragma unroll
    for (int t = 0; t < 4; t++) { aD[t] = (f32x4){0.f,0.f,0.f,0.f}; aO[t] = (f32x4){0.f,0.f,0.f,0.f}; }
    #pragma unroll
    for (int ks = 0; ks < 2; ks++) {
        short8 ga = *(const short8*)(&Gs[qb + rr][ks * 32 + quad * 8]);
        short8 ca = *(const short8*)(&Cs[qb + rr][ks * 32 + quad * 8]);
        #pragma unroll
        for (int t = 0; t < 4; t++) {
            short8 xb = *(const short8*)(&Xt[t * 16 + rr][ks * 32 + quad * 8]);
            short8 sh = *(const short8*)(&Shi[t * 16 + rr][ks * 32 + quad * 8]);
            short8 sl = *(const short8*)(&Slo[t * 16 + rr][ks * 32 + quad * 8]);
            aD[t] = __builtin_amdgcn_mfma_f32_16x16x32_bf16(ga, xb, aD[t], 0, 0, 0);
            aO[t] = __builtin_amdgcn_mfma_f32_16x16x32_bf16(ca, sh, aO[t], 0, 0, 0);
            aO[t] = __builtin_amdgcn_mfma_f32_16x16x32_bf16(ca, sl, aO[t], 0, 0, 0);
        }
    }
    #pragma unroll
    for (int t = 0; t < 4; t++) {
        int p = t * 16 + rr;
        #pragma unroll
        for (int r2 = 0; r2 < 4; r2++) {
            int qq = qb + quad * 4 + r2;
            float y = aD[t][r2] + ea_s[qq] * aO[t][r2] + Dh * b2f(Xt[p][qq]);
            ybuf[(size_t)(b * 1024 + l0 + qq) * 512 + h * 64 + p] = f2b(y);
        }
    }
}

// ---------------- gate: y = y*silu(z), RMSnorm*gw (in-place bf16) ----------------
__global__ __launch_bounds__(256) void gate_kernel(const ushort_t* __restrict__ zbuf,
        ushort_t* __restrict__ ybuf, const float* __restrict__ gw) {
    int r = blockIdx.x, tid = threadIdx.x;
    size_t base = (size_t)r * 512;
    float z0 = b2f(zbuf[base + tid]);
    float z1 = b2f(zbuf[base + tid + 256]);
    float v0 = b2f(ybuf[base + tid]) * silu_f(z0);
    float v1 = b2f(ybuf[base + tid + 256]) * silu_f(z1);
    float ss = v0 * v0 + v1 * v1;
    __shared__ float red[4];
    for (int o = 32; o > 0; o >>= 1) ss += __shfl_down(ss, o, 64);
    if ((tid & 63) == 0) red[tid >> 6] = ss;
    __syncthreads();
    float tot = red[0] + red[1] + red[2] + red[3];
    float rms = rsqrtf(tot * (1.f / 512.f) + 1e-5f);
    ybuf[base + tid] = f2b(v0 * rms * gw[tid]);
    ybuf[base + tid + 256] = f2b(v1 * rms * gw[tid + 256]);
}

// ---------------- residual + layernorm ----------------
__global__ __launch_bounds__(256) void resln_kernel(float* __restrict__ h,
        ushort_t* __restrict__ hbf, const float* __restrict__ yp,
        const float* __restrict__ g, const float* __restrict__ bb) {
    int r = blockIdx.x, tid = threadIdx.x;
    size_t base = (size_t)r * 256;
    float x = h[base + tid] + yp[base + tid];
    float s = x, s2 = x * x;
    __shared__ float r1[4], r2[4];
    for (int o = 32; o > 0; o >>= 1) { s += __shfl_down(s, o, 64); s2 += __shfl_down(s2, o, 64); }
    if ((tid & 63) == 0) { r1[tid >> 6] = s; r2[tid >> 6] = s2; }
    __syncthreads();
    float S = r1[0] + r1[1] + r1[2] + r1[3];
    float S2 = r2[0] + r2[1] + r2[2] + r2[3];
    float mu = S * (1.f / 256.f);
    float var = S2 * (1.f / 256.f) - mu * mu;
    float o = (x - mu) * rsqrtf(var + 1e-5f) * g[tid] + bb[tid];
    h[base + tid] = o;
    hbf[base + tid] = f2b(o);
}

// ---------------- head ----------------
__global__ __launch_bounds__(256) void head_kernel(const float* __restrict__ h,
        const float* __restrict__ hw, const float* __restrict__ stdb,
        const float* __restrict__ meanb, float* __restrict__ out) {
    int blk = blockIdx.x;       // b*192 + t
    int b = blk / 192, t = blk - b * 192;
    int l = 832 + t;
    int tid = threadIdx.x;
    __shared__ float hr[256];
    hr[tid] = h[(size_t)(b * 1024 + l) * 256 + tid];
    __syncthreads();
    if (tid < 21) {
        float acc = 0.f;
        for (int k = 0; k < 256; k++) acc += hr[k] * hw[tid * 256 + k];
        out[(size_t)blk * 21 + tid] = acc * stdb[b * 21 + tid] + meanb[b * 21 + tid];
    }
}

extern "C" void kernel_launch(void* const* d_in, const int* in_sizes, int n_in,
                              void* d_out, int out_size, void* d_ws, size_t ws_size,
                              hipStream_t stream) {
    const float* x_enc  = (const float*)d_in[0];
    const float* x_mark = (const float*)d_in[1];
    const float* tokw   = (const float*)d_in[4];
    const float* tembw  = (const float*)d_in[5];
    const float* ln_g   = (const float*)d_in[6];
    const float* ln_b   = (const float*)d_in[7];
    const float* ipw    = (const float*)d_in[8];
    const float* cw     = (const float*)d_in[9];
    const float* cb     = (const float*)d_in[10];
    const float* dtb    = (const float*)d_in[11];
    const float* alog   = (const float*)d_in[12];
    const float* dsk    = (const float*)d_in[13];
    const float* gw     = (const float*)d_in[14];
    const float* opw    = (const float*)d_in[15];
    const float* hw     = (const float*)d_in[16];
    float* out = (float*)d_out;

    char* w = (char*)d_ws;
    size_t off = 0;
    auto alloc = [&](size_t bytes) -> void* {
        void* p = w + off;
        off += (bytes + 255) & ~(size_t)255;
        return p;
    };
    float* meanb  = (float*)alloc(672 * 4);
    float* stdb   = (float*)alloc(672 * 4);
    float* rstdb  = (float*)alloc(672 * 4);
    float* dts    = (float*)alloc((size_t)262144 * 4);            // 1.05 MB
    float* pebuf  = (float*)alloc((size_t)262144 * 4);            // 1.05 MB
    float* cwt    = (float*)alloc((size_t)10240 * 4);             // 40 KB
    float* hbuf   = (float*)alloc((size_t)8388608 * 4);           // 33.55 MB
    ushort_t* hbf = (ushort_t*)alloc((size_t)8388608 * 2);        // 16.78 MB
    ushort_t* zbuf= (ushort_t*)alloc((size_t)32768 * 512 * 2);    // 33.55 MB
    ushort_t* xc  = (ushort_t*)alloc((size_t)32768 * 640 * 2);    // 41.94 MB
    char* R       = (char*)alloc((size_t)71303168);               // 71.30 MB union
    ushort_t* ybuf= (ushort_t*)alloc((size_t)32768 * 512 * 2);    // 33.55 MB
    ushort_t* wipb= (ushort_t*)alloc((size_t)4 * 1280 * 256 * 2); // 2.62 MB
    ushort_t* wopb= (ushort_t*)alloc((size_t)4 * 256 * 512 * 2);  // 1.05 MB
    // region R aliases: xbuf (gemm_ip out) dies after conv+dt; stbuf/acbuf take over
    ushort_t* xbuf = (ushort_t*)R;                        // 32768 x 704 bf16 = 46.14 MB
    float* stbuf   = (float*)R;                           // 256*16*4096 fp32 = 67.11 MB
    float* acbuf   = (float*)(R + 67108864);              // 256*16*64 fp32 = 4.19 MB
    float* yproj   = (float*)xc;                          // alias: xc dead once gemm_op runs
    (void)ws_size; (void)in_sizes; (void)n_in; (void)out_size;
    // total ~236.5 MB

    stats_kernel<<<672, 256, 0, stream>>>(x_enc, meanb, stdb, rstdb);
    pe_kernel<<<1024, 256, 0, stream>>>(pebuf);
    cvt_pad_ip<<<5120, 256, 0, stream>>>(ipw, wipb);
    cvt_kernel<<<2048, 256, 0, stream>>>(opw, wopb, 524288);
    cvt_convw<<<40, 256, 0, stream>>>(cw, cwt);
    embed3_kernel<<<512, 256, 0, stream>>>(x_enc, x_mark, tokw, tembw, pebuf,
                                           meanb, rstdb, hbuf, hbf);

    for (int layer = 0; layer < 4; layer++) {
        // in_proj: 256 m-tiles x 10 n-tiles = 2560 blocks (128x128 tile)
        gemm_ip<<<2560, 256, 0, stream>>>(hbf, wipb + (size_t)layer * 1280 * 256, zbuf, xbuf);
        conv_kernel<<<2560, 256, 0, stream>>>(xbuf, cwt + layer * 2560, cb + layer * 640, xc);
        dt_kernel<<<1024, 256, 0, stream>>>(xbuf, dtb + layer * 8, dts);
        // xbuf now dead -> stbuf/acbuf overwrite region R
        ssd_stateA<<<4096, 256, 0, stream>>>(xc, dts, alog + layer * 8, stbuf, acbuf);
        ssd_scan<<<1024, 256, 0, stream>>>(stbuf, acbuf);
        ssd_outBC<<<4096, 256, 0, stream>>>(xc, dts, alog + layer * 8, dsk + layer * 8,
                                            stbuf, ybuf);
        gate_kernel<<<32768, 256, 0, stream>>>(zbuf, ybuf, gw + layer * 512);
        // out_proj: 256 m-tiles x 2 n-tiles = 512 blocks
        gemm_op<<<512, 256, 0, stream>>>(ybuf, wopb + (size_t)layer * 256 * 512, yproj);
        resln_kernel<<<32768, 256, 0, stream>>>(hbuf, hbf, yproj,
                                                ln_g + layer * 256, ln_b + layer * 256);
    }

    head_kernel<<<6144, 256, 0, stream>>>(hbuf, hw, stdb, meanb, out);
}

// Round 8
// 974.990 us; speedup vs baseline: 3.8717x; 1.0393x over previous
//
#include <hip/hip_runtime.h>
#include <hip/hip_bf16.h>

// Model: 4-layer Mamba2 TS model. B=32 L=1024 DM=256 DI=512 DST=64 NH=8 HD=64
// DC=4 Q=64 chunks=16 DIP=1160(pad 1280) CONVD=640 PRED=192 CO=21.
// I/O fp32. bf16 MFMA operands, fp32 accum. WS ~236.5 MB.
// R7->R8: XCD-aware tile swizzle in both GEMMs (R7 FETCH=70MB vs 17.5MB
// compulsory: A re-fetched per XCD since n-tiles of one m-tile spread across
// 8 non-coherent L2s). dt fused into gemm_ip epilogue (bf16 roundtrip keeps
// numerics identical). gate/resln vectorized wave-per-row (16B/lane).

typedef unsigned short ushort_t;
typedef unsigned int uint_t;
typedef __attribute__((ext_vector_type(8))) short short8;
typedef __attribute__((ext_vector_type(4))) float f32x4;
typedef __attribute__((ext_vector_type(4))) ushort_t ushort4_t;

__device__ __forceinline__ float b2f(ushort_t u) {
    uint_t v = ((uint_t)u) << 16;
    return __builtin_bit_cast(float, v);
}
__device__ __forceinline__ ushort_t f2b(float f) {
    uint_t u = __builtin_bit_cast(uint_t, f);
    uint_t r = (u + 0x7FFFu + ((u >> 16) & 1u)) >> 16;
    return (ushort_t)r;
}
__device__ __forceinline__ float silu_f(float x) {
    return x / (1.f + __expf(-x));
}
__device__ __forceinline__ void gl_lds16(const ushort_t* g, ushort_t* l) {
    __builtin_amdgcn_global_load_lds(
        (const __attribute__((address_space(1))) unsigned int*)g,
        (__attribute__((address_space(3))) unsigned int*)l, 16, 0, 0);
}

// ---------------- weight converts ----------------
__global__ __launch_bounds__(256) void cvt_kernel(const float* __restrict__ in,
        ushort_t* __restrict__ out, int n) {
    int i = blockIdx.x * 256 + threadIdx.x;
    if (i < n) out[i] = f2b(in[i]);
}
// in_proj w: [4][1160][256] -> bf16 [4][1280][256], rows >=1160 zero
__global__ __launch_bounds__(256) void cvt_pad_ip(const float* __restrict__ in,
        ushort_t* __restrict__ out) {
    int i = blockIdx.x * 256 + threadIdx.x;     // < 4*1280*256
    if (i >= 4 * 1280 * 256) return;
    int layer = i / (1280 * 256);
    int rem = i - layer * 1280 * 256;
    int n = rem >> 8, k = rem & 255;
    out[i] = (n < 1160) ? f2b(in[(size_t)layer * 1160 * 256 + n * 256 + k]) : (ushort_t)0;
}
// conv w: [4][640][4] -> [4][4][640] fp32 transpose
__global__ __launch_bounds__(256) void cvt_convw(const float* __restrict__ in,
        float* __restrict__ out) {
    int i = blockIdx.x * 256 + threadIdx.x;     // < 4*2560
    if (i >= 10240) return;
    int layer = i / 2560;
    int rem = i - layer * 2560;
    int k = rem / 640, ch = rem - k * 640;
    out[i] = in[layer * 2560 + ch * 4 + k];
}

// ---------------- pos-emb table: pe[l][d], computed once ----------------
__global__ __launch_bounds__(256) void pe_kernel(float* __restrict__ pe) {
    int l = blockIdx.x, d = threadIdx.x;
    float div = __expf((float)(d & ~1) * (-9.210340371976184f / 256.0f));
    float arg = (float)l * div;
    pe[l * 256 + d] = (d & 1) ? cosf(arg) : sinf(arg);
}

// ---------------- stats ----------------
__global__ __launch_bounds__(256) void stats_kernel(const float* __restrict__ xe,
        float* __restrict__ meanb, float* __restrict__ stdb, float* __restrict__ rstdb) {
    int bi = blockIdx.x;
    int b = bi / 21, c = bi - b * 21;
    int tid = threadIdx.x;
    float s = 0.f, s2 = 0.f;
    for (int l = tid; l < 1024; l += 256) {
        float v = xe[(b * 1024 + l) * 21 + c];
        s += v; s2 += v * v;
    }
    __shared__ float r1[4], r2[4];
    for (int o = 32; o > 0; o >>= 1) { s += __shfl_down(s, o, 64); s2 += __shfl_down(s2, o, 64); }
    if ((tid & 63) == 0) { r1[tid >> 6] = s; r2[tid >> 6] = s2; }
    __syncthreads();
    if (tid == 0) {
        float S = r1[0] + r1[1] + r1[2] + r1[3];
        float S2 = r2[0] + r2[1] + r2[2] + r2[3];
        float m = S * (1.f / 1024.f);
        float var = S2 * (1.f / 1024.f) - m * m;
        float sd = sqrtf(var + 1e-5f);
        meanb[bi] = m; stdb[bi] = sd; rstdb[bi] = 1.f / sd;
    }
}

// ---------------- embedding: sliding-window, tokw in registers ----------------
__global__ __launch_bounds__(256) void embed3_kernel(const float* __restrict__ xe,
        const float* __restrict__ xm, const float* __restrict__ tokw,
        const float* __restrict__ tembw, const float* __restrict__ pe,
        const float* __restrict__ meanb, const float* __restrict__ rstdb,
        float* __restrict__ h, ushort_t* __restrict__ hbf) {
    int blk = blockIdx.x;               // b*16 + tile
    int b = blk >> 4, t = blk & 15;
    int l0 = t * 64;
    int tid = threadIdx.x;              // = d
    __shared__ float xw[66][22];        // normalized x window, row0 = l0-1 (wrap)
    __shared__ float xmw[64][4];
    __shared__ float mn[21], rs[21];
    if (tid < 21) { mn[tid] = meanb[b * 21 + tid]; rs[tid] = rstdb[b * 21 + tid]; }
    float twr[63];
    {
        const float* tp = tokw + tid * 63;
        #pragma unroll
        for (int i = 0; i < 63; i++) twr[i] = tp[i];
    }
    float tbr[4];
    #pragma unroll
    for (int k = 0; k < 4; k++) tbr[k] = tembw[tid * 4 + k];
    __syncthreads();
    for (int i = tid; i < 1386; i += 256) {
        int row = i / 21, c = i - row * 21;
        int gl = (l0 - 1 + row + 1024) & 1023;
        xw[row][c] = (xe[(size_t)(b * 1024 + gl) * 21 + c] - mn[c]) * rs[c];
    }
    {
        int row = tid >> 2, c = tid & 3;
        xmw[row][c] = xm[(size_t)(b * 1024 + l0 + row) * 4 + c];
    }
    __syncthreads();
    int d = tid;
    float acc2 = 0.f, acc1 = 0.f;   // pending partial sums for out[r-2], out[r-1]
    for (int r = 0; r < 66; r++) {
        float s0 = 0.f, s1 = 0.f, s2 = 0.f;
        #pragma unroll
        for (int c = 0; c < 21; c++) {
            float xv = xw[r][c];
            s0 += xv * twr[c * 3 + 0];
            s1 += xv * twr[c * 3 + 1];
            s2 += xv * twr[c * 3 + 2];
        }
        if (r >= 2) {
            int li = r - 2;
            float acc = acc2 + s2 + pe[(size_t)(l0 + li) * 256 + d];
            #pragma unroll
            for (int k = 0; k < 4; k++) acc += xmw[li][k] * tbr[k];
            size_t o = (size_t)(b * 1024 + l0 + li) * 256 + d;
            h[o] = acc;
            hbf[o] = f2b(acc);
        }
        acc2 = acc1 + s1;
        acc1 = s0;
    }
}

// ---------------- 128x128 LDS-staged GEMM mainloop (m97 structure) ----------------
template<int KDIM>
__device__ __forceinline__ void gemm128_main(const ushort_t* __restrict__ Ab,
        const ushort_t* __restrict__ Wb, ushort_t* sA, ushort_t* sW,
        f32x4 (&acc)[16], int m0, int n0) {
    int tid = threadIdx.x;
    int w = tid >> 6, lane = tid & 63;
    int wm = w >> 1, wn = w & 1;
    int rr = lane & 15, quad = lane >> 4;
    int srow0 = w * 32 + (lane >> 2);       // staging row (+ j*16)
    int skk = (lane & 3) * 8;               // staging k-offset (shorts)
    int sl0 = w * 1024 + lane * 8;          // staging LDS index (+ j*512)
    for (int k0 = 0; k0 < KDIM; k0 += 32) {
        __syncthreads();                    // prev MFMA reads done before overwrite
        #pragma unroll
        for (int j = 0; j < 2; j++) {
            int row = srow0 + j * 16;
            gl_lds16(Ab + (size_t)(m0 + row) * KDIM + k0 + skk, &sA[sl0 + j * 512]);
            gl_lds16(Wb + (size_t)(n0 + row) * KDIM + k0 + skk, &sW[sl0 + j * 512]);
        }
        __syncthreads();                    // compiler drains vmcnt before barrier
        short8 a[4], b[4];
        #pragma unroll
        for (int i = 0; i < 4; i++)
            a[i] = *(const short8*)&sA[(wm * 64 + i * 16 + rr) * 32 + quad * 8];
        #pragma unroll
        for (int j = 0; j < 4; j++)
            b[j] = *(const short8*)&sW[(wn * 64 + j * 16 + rr) * 32 + quad * 8];
        #pragma unroll
        for (int i = 0; i < 4; i++)
            #pragma unroll
            for (int j = 0; j < 4; j++)
                acc[i * 4 + j] = __builtin_amdgcn_mfma_f32_16x16x32_bf16(a[i], b[j], acc[i * 4 + j], 0, 0, 0);
    }
}

// in_proj: A[32768x256] x W[1280x256] -> z (n<512) | xBC (512<=n<1152) | dt fused
__global__ __launch_bounds__(256) void gemm_ip(const ushort_t* __restrict__ A,
        const ushort_t* __restrict__ W, ushort_t* __restrict__ zbuf,
        ushort_t* __restrict__ xbuf, const float* __restrict__ dtb,
        float* __restrict__ dts) {
    // XCD-aware swizzle: blk%8 = XCD (round-robin dispatch assumption);
    // each XCD owns m-tiles [xcd*32, xcd*32+32) and walks all 10 n-tiles,
    // so the A band stays resident in that XCD's L2.
    int blk = blockIdx.x;               // 2560
    int xcd = blk & 7, idx = blk >> 3;  // idx < 320
    int tml = idx / 10, tn = idx - tml * 10;
    int m0 = (xcd * 32 + tml) * 128, n0 = tn * 128;
    __shared__ ushort_t sA[4096], sW[4096];
    f32x4 acc[16];
    #pragma unroll
    for (int i = 0; i < 16; i++) acc[i] = (f32x4){0.f, 0.f, 0.f, 0.f};
    gemm128_main<256>(A, W, sA, sW, acc, m0, n0);
    int lane = threadIdx.x & 63, w = threadIdx.x >> 6;
    int wm = w >> 1, wn = w & 1;
    int rr = lane & 15, quad = lane >> 4;
    #pragma unroll
    for (int i = 0; i < 4; i++) {
        int mrow = m0 + wm * 64 + i * 16 + quad * 4;
        #pragma unroll
        for (int j = 0; j < 4; j++) {
            int n = n0 + wn * 64 + j * 16 + rr;
            #pragma unroll
            for (int r2 = 0; r2 < 4; r2++) {
                ushort_t v = f2b(acc[i * 4 + j][r2]);
                if (n < 512) zbuf[(size_t)(mrow + r2) * 512 + n] = v;
                else if (n < 1152) xbuf[(size_t)(mrow + r2) * 704 + (n - 512)] = v;
                else if (n < 1160) {
                    // fused dt: bf16 roundtrip keeps numerics identical to the
                    // old store->load->softplus path
                    float x = b2f(v) + dtb[n - 1152];
                    dts[(size_t)(mrow + r2) * 8 + (n - 1152)] =
                        (x > 20.f) ? x : log1pf(__expf(x));
                }
            }
        }
    }
}

// out_proj: A[32768x512] x W[256x512] -> C[32768x256] fp32
__global__ __launch_bounds__(256) void gemm_op(const ushort_t* __restrict__ A,
        const ushort_t* __restrict__ W, float* __restrict__ C) {
    int blk = blockIdx.x;               // 512
    int xcd = blk & 7, idx = blk >> 3;  // idx < 64
    int tn = idx & 1;
    int m0 = (xcd * 32 + (idx >> 1)) * 128, n0 = tn * 128;
    __shared__ ushort_t sA[4096], sW[4096];
    f32x4 acc[16];
    #pragma unroll
    for (int i = 0; i < 16; i++) acc[i] = (f32x4){0.f, 0.f, 0.f, 0.f};
    gemm128_main<512>(A, W, sA, sW, acc, m0, n0);
    int lane = threadIdx.x & 63, w = threadIdx.x >> 6;
    int wm = w >> 1, wn = w & 1;
    int rr = lane & 15, quad = lane >> 4;
    #pragma unroll
    for (int i = 0; i < 4; i++) {
        int mrow = m0 + wm * 64 + i * 16 + quad * 4;
        #pragma unroll
        for (int j = 0; j < 4; j++) {
            int n = n0 + wn * 64 + j * 16 + rr;
            #pragma unroll
            for (int r2 = 0; r2 < 4; r2++)
                C[(size_t)(mrow + r2) * 256 + n] = acc[i * 4 + j][r2];
        }
    }
}

// ---------------- causal depthwise conv + bias + silu ----------------
__global__ __launch_bounds__(256) void conv_kernel(const ushort_t* __restrict__ xbuf,
        const float* __restrict__ cwt, const float* __restrict__ cb,
        ushort_t* __restrict__ xc) {
    int idx = blockIdx.x * 256 + threadIdx.x;   // < 8192*80
    int g = idx % 80;
    int rt = idx / 80;
    int ch0 = g * 8;
    int b = rt >> 8;
    int l0 = (rt & 255) << 2;
    float wgt[4][8];
    #pragma unroll
    for (int k = 0; k < 4; k++) {
        float4 w0 = *(const float4*)(cwt + k * 640 + ch0);
        float4 w1 = *(const float4*)(cwt + k * 640 + ch0 + 4);
        wgt[k][0] = w0.x; wgt[k][1] = w0.y; wgt[k][2] = w0.z; wgt[k][3] = w0.w;
        wgt[k][4] = w1.x; wgt[k][5] = w1.y; wgt[k][6] = w1.z; wgt[k][7] = w1.w;
    }
    float bias[8];
    {
        float4 b0 = *(const float4*)(cb + ch0);
        float4 b1 = *(const float4*)(cb + ch0 + 4);
        bias[0] = b0.x; bias[1] = b0.y; bias[2] = b0.z; bias[3] = b0.w;
        bias[4] = b1.x; bias[5] = b1.y; bias[6] = b1.z; bias[7] = b1.w;
    }
    short8 xr[7];
    const ushort_t* base = xbuf + (size_t)(b * 1024 + l0) * 704 + ch0;
    #pragma unroll
    for (int i = 0; i < 7; i++) {
        int ll = l0 - 3 + i;
        if (ll >= 0) xr[i] = *(const short8*)(base + (ptrdiff_t)(i - 3) * 704);
        else         xr[i] = (short8){0, 0, 0, 0, 0, 0, 0, 0};
    }
    #pragma unroll
    for (int lo = 0; lo < 4; lo++) {
        float acc[8];
        #pragma unroll
        for (int j = 0; j < 8; j++) acc[j] = bias[j];
        #pragma unroll
        for (int k = 0; k < 4; k++) {
            #pragma unroll
            for (int j = 0; j < 8; j++)
                acc[j] += b2f(((ushort_t*)&xr[lo + k])[j]) * wgt[k][j];
        }
        short8 o;
        #pragma unroll
        for (int j = 0; j < 8; j++) ((ushort_t*)&o)[j] = f2b(silu_f(acc[j]));
        *(short8*)(xc + (size_t)(b * 1024 + l0 + lo) * 640 + ch0) = o;
    }
}

// ---------------- SSD A: chunk states = (B*dec)^T @ X per (b,h,chunk) ----------------
__global__ __launch_bounds__(256) void ssd_stateA(const ushort_t* __restrict__ xc,
        const float* __restrict__ dts, const float* __restrict__ alog,
        float* __restrict__ stbuf, float* __restrict__ acbuf) {
    int idx = blockIdx.x;               // bh*16 + chunk
    int bh = idx >> 4, chunk = idx & 15;
    int b = bh >> 3, h = bh & 7;
    int l0 = chunk * 64;
    float Ah = -__expf(alog[h]);
    int tid = threadIdx.x;
    int q = tid >> 2, pb = (tid & 3) * 16;

    __shared__ ushort_t Bt[64][72], Xt[64][72];
    __shared__ float dec_s[64];

    const ushort_t* xrow = xc + (size_t)(b * 1024 + l0 + q) * 640;
    ushort_t bv[16], xv[16];
    *(short8*)&bv[0] = *(const short8*)(xrow + 512 + pb);
    *(short8*)&bv[8] = *(const short8*)(xrow + 512 + pb + 8);
    *(short8*)&xv[0] = *(const short8*)(xrow + h * 64 + pb);
    *(short8*)&xv[8] = *(const short8*)(xrow + h * 64 + pb + 8);
    #pragma unroll
    for (int j = 0; j < 16; j++) Xt[pb + j][q] = xv[j];

    if (tid < 64) {
        float d = dts[(size_t)(b * 1024 + l0 + tid) * 8 + h];
        float a = d * Ah;
        #pragma unroll
        for (int off = 1; off < 64; off <<= 1) {
            float t = __shfl_up(a, off, 64);
            if (tid >= off) a += t;
        }
        acbuf[(size_t)idx * 64 + tid] = a;
        float tot = __shfl(a, 63, 64);
        dec_s[tid] = __expf(tot - a) * d;
    }
    __syncthreads();
    {
        float dq = dec_s[q];
        #pragma unroll
        for (int j = 0; j < 16; j++) Bt[pb + j][q] = f2b(b2f(bv[j]) * dq);
    }
    __syncthreads();

    int w = tid >> 6, lane = tid & 63;
    int rr = lane & 15, quad = lane >> 4, qb = w * 16;
    f32x4 acc[4];
    #pragma unroll
    for (int t = 0; t < 4; t++) acc[t] = (f32x4){0.f, 0.f, 0.f, 0.f};
    #pragma unroll
    for (int ks = 0; ks < 2; ks++) {
        short8 a = *(const short8*)(&Bt[qb + rr][ks * 32 + quad * 8]);
        #pragma unroll
        for (int t = 0; t < 4; t++) {
            short8 bb = *(const short8*)(&Xt[t * 16 + rr][ks * 32 + quad * 8]);
            acc[t] = __builtin_amdgcn_mfma_f32_16x16x32_bf16(a, bb, acc[t], 0, 0, 0);
        }
    }
    float* sb = stbuf + (size_t)idx * 4096;
    #pragma unroll
    for (int t = 0; t < 4; t++) {
        int p = t * 16 + rr;
        #pragma unroll
        for (int r2 = 0; r2 < 4; r2++) {
            int nn = qb + quad * 4 + r2;
            sb[nn * 64 + p] = acc[t][r2];
        }
    }
}

// ---------------- SSD B: scan chunk states in place (4-way split) ----------------
__global__ __launch_bounds__(256) void ssd_scan(float* __restrict__ stbuf,
        const float* __restrict__ acbuf) {
    int bh = blockIdx.x >> 2, sl = blockIdx.x & 3;
    int tid = threadIdx.x;
    size_t boff = (size_t)sl * 1024 + tid * 4;
    float4 S = make_float4(0.f, 0.f, 0.f, 0.f);
    for (int c = 0; c < 16; c++) {
        float* p = stbuf + ((size_t)bh * 16 + c) * 4096 + boff;
        float ad = __expf(acbuf[((size_t)bh * 16 + c) * 64 + 63]);
        float4 v = *(float4*)p;
        *(float4*)p = S;
        S.x = ad * S.x + v.x; S.y = ad * S.y + v.y;
        S.z = ad * S.z + v.z; S.w = ad * S.w + v.w;
    }
}

// ---------------- SSD C: y = Y_diag + Y_off + D*x -> bf16 ----------------
__global__ __launch_bounds__(256) void ssd_outBC(const ushort_t* __restrict__ xc,
        const float* __restrict__ dts, const float* __restrict__ alog,
        const float* __restrict__ dsk, const float* __restrict__ stbuf,
        ushort_t* __restrict__ ybuf) {
    int idx = blockIdx.x;
    int bh = idx >> 4, chunk = idx & 15;
    int b = bh >> 3, h = bh & 7;
    int l0 = chunk * 64;
    float Ah = -__expf(alog[h]);
    float Dh = dsk[h];
    int tid = threadIdx.x;
    int q = tid >> 2, pb = (tid & 3) * 16;

    __shared__ ushort_t Cs[64][72], Bs[64][72], Xt[64][72], Gs[64][72], Shi[64][72], Slo[64][72];
    __shared__ float acum_s[64], dtq_s[64], ea_s[64];

    const ushort_t* xrow = xc + (size_t)(b * 1024 + l0 + q) * 640;
    *(short8*)&Bs[q][pb]     = *(const short8*)(xrow + 512 + pb);
    *(short8*)&Bs[q][pb + 8] = *(const short8*)(xrow + 512 + pb + 8);
    *(short8*)&Cs[q][pb]     = *(const short8*)(xrow + 576 + pb);
    *(short8*)&Cs[q][pb + 8] = *(const short8*)(xrow + 576 + pb + 8);
    ushort_t xv[16];
    *(short8*)&xv[0] = *(const short8*)(xrow + h * 64 + pb);
    *(short8*)&xv[8] = *(const short8*)(xrow + h * 64 + pb + 8);
    #pragma unroll
    for (int j = 0; j < 16; j++) Xt[pb + j][q] = xv[j];
    {
        const float* sp = stbuf + (size_t)idx * 4096 + q * 64 + pb;
        #pragma unroll
        for (int j = 0; j < 16; j++) {
            float s = sp[j];
            ushort_t hi = f2b(s);
            Shi[pb + j][q] = hi;
            Slo[pb + j][q] = f2b(s - b2f(hi));
        }
    }
    if (tid < 64) {
        float d = dts[(size_t)(b * 1024 + l0 + tid) * 8 + h];
        dtq_s[tid] = d;
        float a = d * Ah;
        #pragma unroll
        for (int off = 1; off < 64; off <<= 1) {
            float t = __shfl_up(a, off, 64);
            if (tid >= off) a += t;
        }
        acum_s[tid] = a;
        ea_s[tid] = __expf(a);
    }
    __syncthreads();

    int w = tid >> 6, lane = tid & 63;
    int rr = lane & 15, quad = lane >> 4, qb = w * 16;

    // mm1: G = C.B^T masked -> Gs bf16
    {
        f32x4 g[4];
        #pragma unroll
        for (int t = 0; t < 4; t++) g[t] = (f32x4){0.f, 0.f, 0.f, 0.f};
        #pragma unroll
        for (int ks = 0; ks < 2; ks++) {
            short8 a = *(const short8*)(&Cs[qb + rr][ks * 32 + quad * 8]);
            #pragma unroll
            for (int t = 0; t < 4; t++) {
                short8 bb = *(const short8*)(&Bs[t * 16 + rr][ks * 32 + quad * 8]);
                g[t] = __builtin_amdgcn_mfma_f32_16x16x32_bf16(a, bb, g[t], 0, 0, 0);
            }
        }
        #pragma unroll
        for (int t = 0; t < 4; t++) {
            int s = t * 16 + rr;
            float as = acum_s[s], dss = dtq_s[s];
            #pragma unroll
            for (int r2 = 0; r2 < 4; r2++) {
                int qq = qb + quad * 4 + r2;
                float v = (s <= qq) ? g[t][r2] * __expf(acum_s[qq] - as) * dss : 0.f;
                Gs[qq][s] = f2b(v);
            }
        }
    }
    __syncthreads();

    // mm2: Y_diag = G@X ; Y_off = C@(Shi+Slo)
    f32x4 aD[4], aO[4];
    #pragma unroll
    for (int t = 0; t < 4; t++) { aD[t] = (f32x4){0.f,0.f,0.f,0.f}; aO[t] = (f32x4){0.f,0.f,0.f,0.f}; }
    #pragma unroll
    for (int ks = 0; ks < 2; ks++) {
        short8 ga = *(const short8*)(&Gs[qb + rr][ks * 32 + quad * 8]);
        short8 ca = *(const short8*)(&Cs[qb + rr][ks * 32 + quad * 8]);
        #pragma unroll
        for (int t = 0; t < 4; t++) {
            short8 xb = *(const short8*)(&Xt[t * 16 + rr][ks * 32 + quad * 8]);
            short8 sh = *(const short8*)(&Shi[t * 16 + rr][ks * 32 + quad * 8]);
            short8 sl = *(const short8*)(&Slo[t * 16 + rr][ks * 32 + quad * 8]);
            aD[t] = __builtin_amdgcn_mfma_f32_16x16x32_bf16(ga, xb, aD[t], 0, 0, 0);
            aO[t] = __builtin_amdgcn_mfma_f32_16x16x32_bf16(ca, sh, aO[t], 0, 0, 0);
            aO[t] = __builtin_amdgcn_mfma_f32_16x16x32_bf16(ca, sl, aO[t], 0, 0, 0);
        }
    }
    #pragma unroll
    for (int t = 0; t < 4; t++) {
        int p = t * 16 + rr;
        #pragma unroll
        for (int r2 = 0; r2 < 4; r2++) {
            int qq = qb + quad * 4 + r2;
            float y = aD[t][r2] + ea_s[qq] * aO[t][r2] + Dh * b2f(Xt[p][qq]);
            ybuf[(size_t)(b * 1024 + l0 + qq) * 512 + h * 64 + p] = f2b(y);
        }
    }
}

// ---------------- gate: wave-per-row, 16B/lane ----------------
__global__ __launch_bounds__(256) void gate_kernel(const ushort_t* __restrict__ zbuf,
        ushort_t* __restrict__ ybuf, const float* __restrict__ gw) {
    int row = blockIdx.x * 4 + (threadIdx.x >> 6);
    int lane = threadIdx.x & 63;
    size_t base = (size_t)row * 512 + lane * 8;
    short8 zv = *(const short8*)(zbuf + base);
    short8 yv = *(const short8*)(ybuf + base);
    float v[8];
    float ss = 0.f;
    #pragma unroll
    for (int j = 0; j < 8; j++) {
        v[j] = b2f(((ushort_t*)&yv)[j]) * silu_f(b2f(((ushort_t*)&zv)[j]));
        ss += v[j] * v[j];
    }
    #pragma unroll
    for (int o = 1; o < 64; o <<= 1) ss += __shfl_xor(ss, o, 64);
    float rms = rsqrtf(ss * (1.f / 512.f) + 1e-5f);
    float4 g0 = *(const float4*)(gw + lane * 8);
    float4 g1 = *(const float4*)(gw + lane * 8 + 4);
    float gv[8] = {g0.x, g0.y, g0.z, g0.w, g1.x, g1.y, g1.z, g1.w};
    short8 o;
    #pragma unroll
    for (int j = 0; j < 8; j++) ((ushort_t*)&o)[j] = f2b(v[j] * rms * gv[j]);
    *(short8*)(ybuf + base) = o;
}

// ---------------- residual + layernorm: wave-per-row, 16B/lane ----------------
__global__ __launch_bounds__(256) void resln_kernel(float* __restrict__ h,
        ushort_t* __restrict__ hbf, const float* __restrict__ yp,
        const float* __restrict__ g, const float* __restrict__ bb) {
    int row = blockIdx.x * 4 + (threadIdx.x >> 6);
    int lane = threadIdx.x & 63;
    size_t base = (size_t)row * 256 + lane * 4;
    float4 hv = *(const float4*)(h + base);
    float4 yv = *(const float4*)(yp + base);
    float x[4] = {hv.x + yv.x, hv.y + yv.y, hv.z + yv.z, hv.w + yv.w};
    float s = 0.f, s2 = 0.f;
    #pragma unroll
    for (int j = 0; j < 4; j++) { s += x[j]; s2 += x[j] * x[j]; }
    #pragma unroll
    for (int o = 1; o < 64; o <<= 1) { s += __shfl_xor(s, o, 64); s2 += __shfl_xor(s2, o, 64); }
    float mu = s * (1.f / 256.f);
    float var = s2 * (1.f / 256.f) - mu * mu;
    float rstd = rsqrtf(var + 1e-5f);
    float4 gv = *(const float4*)(g + lane * 4);
    float4 bv = *(const float4*)(bb + lane * 4);
    float gr[4] = {gv.x, gv.y, gv.z, gv.w};
    float br[4] = {bv.x, bv.y, bv.z, bv.w};
    float4 ho;
    ushort4_t bo;
    #pragma unroll
    for (int j = 0; j < 4; j++) {
        float o = (x[j] - mu) * rstd * gr[j] + br[j];
        ((float*)&ho)[j] = o;
        bo[j] = f2b(o);
    }
    *(float4*)(h + base) = ho;
    *(ushort4_t*)(hbf + base) = bo;
}

// ---------------- head ----------------
__global__ __launch_bounds__(256) void head_kernel(const float* __restrict__ h,
        const float* __restrict__ hw, const float* __restrict__ stdb,
        const float* __restrict__ meanb, float* __restrict__ out) {
    int blk = blockIdx.x;       // b*192 + t
    int b = blk / 192, t = blk - b * 192;
    int l = 832 + t;
    int tid = threadIdx.x;
    __shared__ float hr[256];
    hr[tid] = h[(size_t)(b * 1024 + l) * 256 + tid];
    __syncthreads();
    if (tid < 21) {
        float acc = 0.f;
        for (int k = 0; k < 256; k++) acc += hr[k] * hw[tid * 256 + k];
        out[(size_t)blk * 21 + tid] = acc * stdb[b * 21 + tid] + meanb[b * 21 + tid];
    }
}

extern "C" void kernel_launch(void* const* d_in, const int* in_sizes, int n_in,
                              void* d_out, int out_size, void* d_ws, size_t ws_size,
                              hipStream_t stream) {
    const float* x_enc  = (const float*)d_in[0];
    const float* x_mark = (const float*)d_in[1];
    const float* tokw   = (const float*)d_in[4];
    const float* tembw  = (const float*)d_in[5];
    const float* ln_g   = (const float*)d_in[6];
    const float* ln_b   = (const float*)d_in[7];
    const float* ipw    = (const float*)d_in[8];
    const float* cw     = (const float*)d_in[9];
    const float* cb     = (const float*)d_in[10];
    const float* dtb    = (const float*)d_in[11];
    const float* alog   = (const float*)d_in[12];
    const float* dsk    = (const float*)d_in[13];
    const float* gw     = (const float*)d_in[14];
    const float* opw    = (const float*)d_in[15];
    const float* hw     = (const float*)d_in[16];
    float* out = (float*)d_out;

    char* w = (char*)d_ws;
    size_t off = 0;
    auto alloc = [&](size_t bytes) -> void* {
        void* p = w + off;
        off += (bytes + 255) & ~(size_t)255;
        return p;
    };
    float* meanb  = (float*)alloc(672 * 4);
    float* stdb   = (float*)alloc(672 * 4);
    float* rstdb  = (float*)alloc(672 * 4);
    float* dts    = (float*)alloc((size_t)262144 * 4);            // 1.05 MB
    float* pebuf  = (float*)alloc((size_t)262144 * 4);            // 1.05 MB
    float* cwt    = (float*)alloc((size_t)10240 * 4);             // 40 KB
    float* hbuf   = (float*)alloc((size_t)8388608 * 4);           // 33.55 MB
    ushort_t* hbf = (ushort_t*)alloc((size_t)8388608 * 2);        // 16.78 MB
    ushort_t* zbuf= (ushort_t*)alloc((size_t)32768 * 512 * 2);    // 33.55 MB
    ushort_t* xc  = (ushort_t*)alloc((size_t)32768 * 640 * 2);    // 41.94 MB
    char* R       = (char*)alloc((size_t)71303168);               // 71.30 MB union
    ushort_t* ybuf= (ushort_t*)alloc((size_t)32768 * 512 * 2);    // 33.55 MB
    ushort_t* wipb= (ushort_t*)alloc((size_t)4 * 1280 * 256 * 2); // 2.62 MB
    ushort_t* wopb= (ushort_t*)alloc((size_t)4 * 256 * 512 * 2);  // 1.05 MB
    // region R aliases: xbuf (gemm_ip out) dies after conv; stbuf/acbuf take over
    ushort_t* xbuf = (ushort_t*)R;                        // 32768 x 704 bf16 = 46.14 MB
    float* stbuf   = (float*)R;                           // 256*16*4096 fp32 = 67.11 MB
    float* acbuf   = (float*)(R + 67108864);              // 256*16*64 fp32 = 4.19 MB
    float* yproj   = (float*)xc;                          // alias: xc dead once gemm_op runs
    (void)ws_size; (void)in_sizes; (void)n_in; (void)out_size;
    // total ~236.5 MB

    stats_kernel<<<672, 256, 0, stream>>>(x_enc, meanb, stdb, rstdb);
    pe_kernel<<<1024, 256, 0, stream>>>(pebuf);
    cvt_pad_ip<<<5120, 256, 0, stream>>>(ipw, wipb);
    cvt_kernel<<<2048, 256, 0, stream>>>(opw, wopb, 524288);
    cvt_convw<<<40, 256, 0, stream>>>(cw, cwt);
    embed3_kernel<<<512, 256, 0, stream>>>(x_enc, x_mark, tokw, tembw, pebuf,
                                           meanb, rstdb, hbuf, hbf);

    for (int layer = 0; layer < 4; layer++) {
        // in_proj: 2560 blocks, XCD-swizzled; dt fused in epilogue
        gemm_ip<<<2560, 256, 0, stream>>>(hbf, wipb + (size_t)layer * 1280 * 256,
                                          zbuf, xbuf, dtb + layer * 8, dts);
        conv_kernel<<<2560, 256, 0, stream>>>(xbuf, cwt + layer * 2560, cb + layer * 640, xc);
        // xbuf now dead -> stbuf/acbuf overwrite region R
        ssd_stateA<<<4096, 256, 0, stream>>>(xc, dts, alog + layer * 8, stbuf, acbuf);
        ssd_scan<<<1024, 256, 0, stream>>>(stbuf, acbuf);
        ssd_outBC<<<4096, 256, 0, stream>>>(xc, dts, alog + layer * 8, dsk + layer * 8,
                                            stbuf, ybuf);
        gate_kernel<<<8192, 256, 0, stream>>>(zbuf, ybuf, gw + layer * 512);
        // out_proj: 512 blocks, XCD-swizzled
        gemm_op<<<512, 256, 0, stream>>>(ybuf, wopb + (size_t)layer * 256 * 512, yproj);
        resln_kernel<<<8192, 256, 0, stream>>>(hbuf, hbf, yproj,
                                               ln_g + layer * 256, ln_b + layer * 256);
    }

    head_kernel<<<6144, 256, 0, stream>>>(hbuf, hw, stdb, meanb, out);
}